// Round 9
// baseline (610.077 us; speedup 1.0000x reference)
//
#include <hip/hip_runtime.h>
#include <hip/hip_fp16.h>
#include <math.h>

#define B_TOT 512
#define CQKV  256
#define CIN   128
#define HLEN  128

static constexpr float F_QR = 0.3f, F_KR = 0.3f, F_SV = 0.5f, F_SVE = 0.3f;
static constexpr float EPS = 1e-5f;

typedef __attribute__((ext_vector_type(8))) short short8v;
typedef __attribute__((ext_vector_type(8))) _Float16 half8v;
typedef __attribute__((ext_vector_type(4))) float float4v;

__device__ __forceinline__ unsigned short f2bf(float f) {
    unsigned u = __float_as_uint(f);
    unsigned r = u + 0x7fffu + ((u >> 16) & 1u);
    return (unsigned short)(r >> 16);
}
__device__ __forceinline__ unsigned short f2h(float f) {
    return __half_as_ushort(__float2half(f));
}

// ---------------------------------------------------------------------------
// Kernel 1 (MFMA): qkv[b][o][h] = sum_c w[o][c] * x[n][c][w][h]  (round-7)
// ---------------------------------------------------------------------------
__global__ __launch_bounds__(256, 3) void k_qkv(const float* __restrict__ x,
                                                const float* __restrict__ w,
                                                float* __restrict__ qkv) {
    __shared__ unsigned short As[64][136];
    __shared__ unsigned short Xs[256][64];
    int bid = blockIdx.x;
    int n   = bid >> 7;
    int sub = bid & 127;
    int mt  = sub >> 2;
    int ot  = sub & 3;
    int m0  = mt << 8;
    int o0  = ot << 6;
    int t   = threadIdx.x;

#pragma unroll
    for (int it = 0; it < 8; ++it) {
        int idx = it * 256 + t;
        int o = idx >> 5, c4 = (idx & 31) << 2;
        float4 wv = *(const float4*)(w + (size_t)(o0 + o) * CIN + c4);
        As[o][c4 + 0] = f2bf(wv.x);
        As[o][c4 + 1] = f2bf(wv.y);
        As[o][c4 + 2] = f2bf(wv.z);
        As[o][c4 + 3] = f2bf(wv.w);
    }

    const float* xn = x + (size_t)n * CIN * 8192 + m0;

    int wv_ = t >> 6, l = t & 63;
    int lr = l & 15, lh = l >> 4;
    int mw = wv_ << 6;

    float4v acc[4][4];
#pragma unroll
    for (int a = 0; a < 4; ++a)
#pragma unroll
        for (int b2 = 0; b2 < 4; ++b2) acc[a][b2] = (float4v){0.f, 0.f, 0.f, 0.f};

    for (int s = 0; s < 2; ++s) {
        int c0 = s << 6;
        __syncthreads();
#pragma unroll
        for (int it = 0; it < 16; ++it) {
            int c  = (it << 2) + (t >> 6);
            int m4 = (t & 63) << 2;
            float4 xv = *(const float4*)(xn + (size_t)(c0 + c) * 8192 + m4);
            float vals[4] = {xv.x, xv.y, xv.z, xv.w};
#pragma unroll
            for (int j = 0; j < 4; ++j) {
                int m = m4 + j;
                int cs = (((c >> 3) ^ ((m >> 2) & 7)) << 3) | (c & 7);
                Xs[m][cs] = f2bf(vals[j]);
            }
        }
        __syncthreads();
#pragma unroll
        for (int ks = 0; ks < 2; ++ks) {
            short8v af[4], bf[4];
#pragma unroll
            for (int a = 0; a < 4; ++a)
                af[a] = *(const short8v*)&As[a * 16 + lr][c0 + ks * 32 + lh * 8];
#pragma unroll
            for (int b2 = 0; b2 < 4; ++b2) {
                int m  = mw + b2 * 16 + lr;
                int cb = (ks * 4 + lh) ^ ((m >> 2) & 7);
                bf[b2] = *(const short8v*)&Xs[m][cb << 3];
            }
#pragma unroll
            for (int a = 0; a < 4; ++a)
#pragma unroll
                for (int b2 = 0; b2 < 4; ++b2)
                    acc[a][b2] = __builtin_amdgcn_mfma_f32_16x16x32_bf16(
                        af[a], bf[b2], acc[a][b2], 0, 0, 0);
        }
    }

#pragma unroll
    for (int a = 0; a < 4; ++a) {
#pragma unroll
        for (int b2 = 0; b2 < 4; ++b2) {
            int m  = m0 + mw + b2 * 16 + lr;
            int bb = n * 64 + (m >> 7);
            int h  = m & 127;
#pragma unroll
            for (int r = 0; r < 4; ++r) {
                int o = o0 + a * 16 + lh * 4 + r;
                qkv[((size_t)bb * CQKV + o) * HLEN + h] = acc[a][b2][r];
            }
        }
    }
}

// ---------------------------------------------------------------------------
// Kernel 2: per-channel stats -> fused affine (scale, shift)
// ---------------------------------------------------------------------------
template <int MODE>
__global__ __launch_bounds__(256) void k_chstats(const float* __restrict__ data,
                                                 const float* __restrict__ ga,
                                                 const float* __restrict__ ba,
                                                 const float* __restrict__ gb,
                                                 const float* __restrict__ bb,
                                                 float* __restrict__ scale,
                                                 float* __restrict__ shift) {
    int o = blockIdx.x;
    int t = threadIdx.x;
    double s = 0.0, ss = 0.0;
    for (int idx = t; idx < B_TOT * HLEN; idx += 256) {
        int b = idx >> 7, h = idx & 127;
        float v = data[((size_t)b * CQKV + o) * HLEN + h];
        s += v;
        ss += (double)v * v;
    }
    __shared__ double sh_s[256], sh_ss[256];
    sh_s[t] = s; sh_ss[t] = ss;
    __syncthreads();
    for (int off = 128; off > 0; off >>= 1) {
        if (t < off) { sh_s[t] += sh_s[t + off]; sh_ss[t] += sh_ss[t + off]; }
        __syncthreads();
    }
    if (t == 0) {
        double cnt  = (double)B_TOT * HLEN;
        double mean = sh_s[0] / cnt;
        double var  = sh_ss[0] / cnt - mean * mean;
        float sc, sf;
        if (MODE == 0) {
            float r1 = rsqrtf((float)var + EPS);
            float v2 = ga[o] * ga[o] * (float)var * r1 * r1;
            sc = ga[o] * gb[o] * r1 * rsqrtf(v2 + EPS);
            sf = bb[o] - (float)mean * sc;
        } else {
            sc = ga[o] * rsqrtf((float)var + EPS);
            sf = ba[o] - (float)mean * sc;
        }
        scale[o] = sc;
        shift[o] = sf;
    }
}

// ---------------------------------------------------------------------------
// Tables for analytic score stats (f32, for k_gram).
// ---------------------------------------------------------------------------
__global__ __launch_bounds__(128) void k_tables(const float* __restrict__ rel,
                                                float* __restrict__ Rq, float* __restrict__ Rk,
                                                float* __restrict__ TqT, float* __restrict__ TkT) {
    int bid = blockIdx.x;      // 0..127
    int i = threadIdx.x;       // 0..127
    int p = bid & 63;
    int c = p >> 3, c2 = p & 7;
    const float* ra = (bid < 64) ? (rel + c * 255)  : (rel + (8 + c) * 255);
    const float* rb = (bid < 64) ? (rel + c2 * 255) : (rel + (8 + c2) * 255);
    float tacc = 0.f;
    for (int kk = 0; kk < 128; ++kk) tacc = fmaf(ra[i + kk], rb[i + kk], tacc);
    if (bid < 64) TqT[i * 64 + p] = tacc; else TkT[i * 64 + p] = tacc;
    if (c2 == 0) {
        float racc = 0.f;
        for (int kk = 0; kk < 128; ++kk) racc += ra[i + kk];
        if (bid < 64) Rq[c * 128 + i] = racc; else Rk[c * 128 + i] = racc;
    }
}

// ---------------------------------------------------------------------------
// relT: 4 tables x [255][8] f16, d-major — L1-resident Toeplitz gathers.
//   table 0: rq (rel rows 0-7), 1: rk (8-15), 2: rvA (16-23), 3: rvB (24-31)
// ---------------------------------------------------------------------------
__global__ void k_relT(const float* __restrict__ rel,
                       unsigned short* __restrict__ relT) {
    int d = blockIdx.x * 64 + threadIdx.x;
    if (d < 255) {
#pragma unroll
        for (int r = 0; r < 32; ++r)
            relT[(size_t)(r >> 3) * 2040 + d * 8 + (r & 7)] = f2h(rel[r * 255 + d]);
    }
}

// ---------------------------------------------------------------------------
// Analytic score stats per (b,g).
// ---------------------------------------------------------------------------
__global__ __launch_bounds__(64) void k_gram(const float* __restrict__ qkv,
                                             const float* __restrict__ scaleA,
                                             const float* __restrict__ shiftA,
                                             const float* __restrict__ Rq,
                                             const float* __restrict__ Rk,
                                             const float* __restrict__ TqT,
                                             const float* __restrict__ TkT,
                                             double* __restrict__ accS) {
    __shared__ float qs[8][132], ks[8][132];
    int blk = blockIdx.x, b = blk >> 3, g = blk & 7;
    int t = threadIdx.x;
    for (int idx = t; idx < 2048; idx += 64) {
        int cc = idx >> 7, h = idx & 127, o = g * 32 + cc;
        float v = qkv[((size_t)b * CQKV + o) * HLEN + h] * scaleA[o] + shiftA[o];
        if (cc < 8) qs[cc][h] = v; else ks[cc - 8][h] = v;
    }
    __syncthreads();
    int c = t >> 3, c2 = t & 7;
    float gq = 0, gk = 0, tq = 0, tk = 0;
    for (int i = 0; i < 128; ++i) {
        float a = qs[c][i] * qs[c2][i];
        float e = ks[c][i] * ks[c2][i];
        gq += a; gk += e;
        tq = fmaf(a, TqT[i * 64 + t], tq);
        tk = fmaf(e, TkT[i * 64 + t], tk);
    }
    float ssqk = gq * gk;
    float sqr = 0, skr = 0;
    float sq8[8], sk8[8];
#pragma unroll
    for (int c3 = 0; c3 < 8; ++c3) {
        float q0 = qs[c3][t], q1 = qs[c3][t + 64];
        float k0 = ks[c3][t], k1 = ks[c3][t + 64];
        sq8[c3] = q0 + q1; sk8[c3] = k0 + k1;
        sqr = fmaf(q0, Rq[c3 * 128 + t], sqr);
        sqr = fmaf(q1, Rq[c3 * 128 + t + 64], sqr);
        skr = fmaf(k0, Rk[c3 * 128 + t], skr);
        skr = fmaf(k1, Rk[c3 * 128 + t + 64], skr);
    }
#pragma unroll
    for (int off = 1; off < 64; off <<= 1) {
        ssqk += __shfl_xor(ssqk, off);
        tq   += __shfl_xor(tq, off);
        tk   += __shfl_xor(tk, off);
        sqr  += __shfl_xor(sqr, off);
        skr  += __shfl_xor(skr, off);
#pragma unroll
        for (int c3 = 0; c3 < 8; ++c3) {
            sq8[c3] += __shfl_xor(sq8[c3], off);
            sk8[c3] += __shfl_xor(sk8[c3], off);
        }
    }
    if (t == 0) {
        float sqk = 0;
#pragma unroll
        for (int c3 = 0; c3 < 8; ++c3) sqk += sq8[c3] * sk8[c3];
        atomicAdd(&accS[g * 2 + 0], (double)sqk);
        atomicAdd(&accS[g * 2 + 1], (double)ssqk);
        atomicAdd(&accS[(8 + g) * 2 + 0], (double)(F_QR * sqr));
        atomicAdd(&accS[(8 + g) * 2 + 1], (double)(F_QR * F_QR * tq));
        atomicAdd(&accS[(16 + g) * 2 + 0], (double)(F_KR * skr));
        atomicAdd(&accS[(16 + g) * 2 + 1], (double)(F_KR * F_KR * tk));
    }
}

__global__ void k_sfin(const double* __restrict__ accS,
                       const float* __restrict__ gs, const float* __restrict__ bs,
                       float* __restrict__ scaleS, float* __restrict__ shiftS) {
    int c = threadIdx.x;
    if (c < 24) {
        double cnt  = 512.0 * 128.0 * 128.0;
        double mean = accS[c * 2] / cnt;
        double var  = accS[c * 2 + 1] / cnt - mean * mean;
        float sc = gs[c] * rsqrtf((float)var + EPS);
        scaleS[c] = sc;
        shiftS[c] = bs[c] - (float)mean * sc;
    }
}

// ---------------------------------------------------------------------------
// Attention (f16 + L1-resident Toeplitz tables):
//  - rel gathers now global f16 [255][8] b128 loads (d consecutive across
//    lanes -> near-coalesced, 16KB total -> L1-hot). Frees 16.3KB LDS and
//    kills the dominant LDS-conflict source.
//  - LDS 43.3KB -> 3 blocks/CU (12 waves, was 8).
// ---------------------------------------------------------------------------
__global__ __launch_bounds__(256, 4) void k_attn(const float* __restrict__ qkv,
                                                 const float* __restrict__ scaleA,
                                                 const float* __restrict__ shiftA,
                                                 const unsigned short* __restrict__ relT,
                                                 const float* __restrict__ scaleS,
                                                 const float* __restrict__ shiftS,
                                                 float* __restrict__ so) {
    __shared__ unsigned short qT[128][8];    // f16, row=i
    __shared__ unsigned short kF[128][8];    // f16, row=j
    __shared__ unsigned short vB[16][136];   // f16, row=c (sv B-frags)
    __shared__ unsigned short Pl[128][136];  // f16 P*rn
    const unsigned short* gRq = relT;
    const unsigned short* gRk = relT + 2040;
    const unsigned short* gVa = relT + 4080;
    const unsigned short* gVb = relT + 6120;

    int blk = blockIdx.x, b = blk >> 3, g = blk & 7;
    int t = threadIdx.x;
    for (int idx = t; idx < 32 * 128; idx += 256) {
        int cc = idx >> 7, h = idx & 127, o = g * 32 + cc;
        float v = qkv[((size_t)b * CQKV + o) * HLEN + h] * scaleA[o] + shiftA[o];
        if (cc < 8)       qT[h][cc] = f2h(v);
        else if (cc < 16) kF[h][cc - 8] = f2h(v);
        else              vB[cc - 16][h] = f2h(v);
    }
    __syncthreads();

    float cA = scaleS[g], cB = F_QR * scaleS[8 + g], cC = F_KR * scaleS[16 + g];
    float shsum = shiftS[g] + shiftS[8 + g] + shiftS[16 + g];

    int i = t >> 1, j0 = (t & 1) << 6;
    __half2 q2[4];
    {
        uint4 qv = *(const uint4*)&qT[i][0];
        q2[0] = *(__half2*)&qv.x; q2[1] = *(__half2*)&qv.y;
        q2[2] = *(__half2*)&qv.z; q2[3] = *(__half2*)&qv.w;
    }

    float p[64];
    float rowmax = -1e30f;
#pragma unroll
    for (int jj = 0; jj < 64; ++jj) {
        int j = j0 + jj;
        uint4 kv = *(const uint4*)&kF[j][0];
        uint4 rq = *(const uint4*)(gRq + (size_t)(i - j + 127) * 8);
        uint4 rk = *(const uint4*)(gRk + (size_t)(j - i + 127) * 8);
        __half2* k2  = (__half2*)&kv;
        __half2* rq2 = (__half2*)&rq;
        __half2* rk2 = (__half2*)&rk;
        __half2 hqk = __hfma2(q2[0], k2[0], __hfma2(q2[1], k2[1],
                      __hfma2(q2[2], k2[2], __hmul2(q2[3], k2[3]))));
        __half2 hqr = __hfma2(q2[0], rq2[0], __hfma2(q2[1], rq2[1],
                      __hfma2(q2[2], rq2[2], __hmul2(q2[3], rq2[3]))));
        __half2 hkr = __hfma2(k2[0], rk2[0], __hfma2(k2[1], rk2[1],
                      __hfma2(k2[2], rk2[2], __hmul2(k2[3], rk2[3]))));
        float qk = __low2float(hqk) + __high2float(hqk);
        float qr = __low2float(hqr) + __high2float(hqr);
        float kr = __low2float(hkr) + __high2float(hkr);
        float s = fmaf(qk, cA, fmaf(qr, cB, fmaf(kr, cC, shsum)));
        p[jj] = s;
        rowmax = fmaxf(rowmax, s);
    }
    rowmax = fmaxf(rowmax, __shfl_xor(rowmax, 1));
    float rsum = 0.f;
#pragma unroll
    for (int jj = 0; jj < 64; ++jj) {
        float e = __expf(p[jj] - rowmax);
        p[jj] = e;
        rsum += e;
    }
    rsum += __shfl_xor(rsum, 1);
    float rn = 1.f / rsum;

    // ---- write P*rn as f16 to LDS ----
#pragma unroll
    for (int k = 0; k < 32; ++k) {
        __half2 h2 = __floats2half2_rn(p[2 * k] * rn, p[2 * k + 1] * rn);
        *(unsigned*)&Pl[i][j0 + 2 * k] = *(unsigned*)&h2;
    }

    // ---- sve = P (*) v_emb: packed f16 MACs, L1 gathers ----
    __half2 acc2[8];
#pragma unroll
    for (int m = 0; m < 8; ++m) acc2[m] = __floats2half2_rn(0.f, 0.f);
#pragma unroll
    for (int jj = 0; jj < 64; ++jj) {
        int j = j0 + jj;
        int d = i - j + 127;
        __half2 p2 = __float2half2_rn(p[jj]);
        uint4 ra = *(const uint4*)(gVa + (size_t)d * 8);
        uint4 rb = *(const uint4*)(gVb + (size_t)d * 8);
        __half2* ra2 = (__half2*)&ra;
        __half2* rb2 = (__half2*)&rb;
        acc2[0] = __hfma2(p2, ra2[0], acc2[0]);
        acc2[1] = __hfma2(p2, ra2[1], acc2[1]);
        acc2[2] = __hfma2(p2, ra2[2], acc2[2]);
        acc2[3] = __hfma2(p2, ra2[3], acc2[3]);
        acc2[4] = __hfma2(p2, rb2[0], acc2[4]);
        acc2[5] = __hfma2(p2, rb2[1], acc2[5]);
        acc2[6] = __hfma2(p2, rb2[2], acc2[6]);
        acc2[7] = __hfma2(p2, rb2[3], acc2[7]);
    }
    float a1[16];
#pragma unroll
    for (int m = 0; m < 8; ++m) {
        a1[2 * m]     = __low2float(acc2[m]);
        a1[2 * m + 1] = __high2float(acc2[m]);
    }
#pragma unroll
    for (int c = 0; c < 16; ++c) a1[c] += __shfl_xor(a1[c], 1);
    {
        int cbase = (t & 1) * 8;
        float sce = F_SVE * rn;
        float* sop = so + ((size_t)b * CQKV + g * 32) * HLEN + i;
#pragma unroll
        for (int c8 = 0; c8 < 8; ++c8) {
            int c = cbase + c8;
            sop[(size_t)(2 * c + 1) * HLEN] = a1[c] * sce;
        }
    }

    __syncthreads();

    // ---- sv via MFMA (f16): D(16i x 16c) = P-tile(16 x 32j) x V(32j x 16c) ----
    {
        int w = t >> 6, l = t & 63;
        int lr = l & 15, lh = l >> 4;
#pragma unroll
        for (int it = 0; it < 2; ++it) {
            int itile = w * 2 + it;
            float4v acc = {0.f, 0.f, 0.f, 0.f};
#pragma unroll
            for (int ks = 0; ks < 4; ++ks) {
                half8v af = *(const half8v*)&Pl[itile * 16 + lr][ks * 32 + lh * 8];
                half8v bf = *(const half8v*)&vB[lr][ks * 32 + lh * 8];
                acc = __builtin_amdgcn_mfma_f32_16x16x32_f16(af, bf, acc, 0, 0, 0);
            }
            int oc = g * 32 + 2 * lr;                       // even slot = sv
            float* sop = so + ((size_t)b * CQKV + oc) * HLEN + itile * 16 + lh * 4;
            float4 outv;
            outv.x = acc[0] * F_SV; outv.y = acc[1] * F_SV;
            outv.z = acc[2] * F_SV; outv.w = acc[3] * F_SV;
            *(float4*)sop = outv;
        }
    }
}

// ---------------------------------------------------------------------------
// Final affine + pair-sum + transpose
// ---------------------------------------------------------------------------
__global__ __launch_bounds__(256) void k_out(const float* __restrict__ so,
                                             const float* __restrict__ scale,
                                             const float* __restrict__ shift,
                                             float* __restrict__ out) {
    int b = blockIdx.x, n = b >> 6, wi = b & 63;
    int t = threadIdx.x, h = t & 127, half = t >> 7;
    for (int oc = half * 64; oc < half * 64 + 64; ++oc) {
        float v0 = so[((size_t)b * CQKV + 2 * oc) * HLEN + h] * scale[2 * oc] + shift[2 * oc];
        float v1 = so[((size_t)b * CQKV + 2 * oc + 1) * HLEN + h] * scale[2 * oc + 1] + shift[2 * oc + 1];
        out[(((size_t)n * 128 + oc) * 64 + wi) * HLEN + h] = v0 + v1;
    }
}

extern "C" void kernel_launch(void* const* d_in, const int* in_sizes, int n_in,
                              void* d_out, int out_size, void* d_ws, size_t ws_size,
                              hipStream_t stream) {
    const float* x   = (const float*)d_in[0];
    const float* w   = (const float*)d_in[1];
    const float* g1  = (const float*)d_in[2];
    const float* b1  = (const float*)d_in[3];
    const float* g2  = (const float*)d_in[4];
    const float* b2  = (const float*)d_in[5];
    const float* gs  = (const float*)d_in[6];
    const float* bs  = (const float*)d_in[7];
    const float* go  = (const float*)d_in[8];
    const float* bo  = (const float*)d_in[9];
    const float* rel = (const float*)d_in[10];
    float* out = (float*)d_out;

    float*  qkv    = (float*)d_ws;                      // 16,777,216 f
    float*  so     = qkv + (size_t)16777216;            // 16,777,216 f
    double* accS   = (double*)(so + (size_t)16777216);  // 48 d
    float*  scaleA = (float*)(accS + 48);
    float*  shiftA = scaleA + 256;
    float*  scaleS = shiftA + 256;                      // 24
    float*  shiftS = scaleS + 24;
    float*  scaleF = shiftS + 24;                       // 256
    float*  shiftF = scaleF + 256;
    float*  Rq     = shiftF + 256;                      // 1024
    float*  Rk     = Rq + 1024;                         // 1024
    float*  TqT    = Rk + 1024;                         // 8192
    float*  TkT    = TqT + 8192;                        // 8192
    unsigned short* relT = (unsigned short*)(TkT + 8192); // 4 x 2040 f16

    hipMemsetAsync(accS, 0, 48 * sizeof(double), stream);

    k_qkv<<<1024, 256, 0, stream>>>(x, w, qkv);
    k_tables<<<128, 128, 0, stream>>>(rel, Rq, Rk, TqT, TkT);
    k_relT<<<4, 64, 0, stream>>>(rel, relT);
    k_chstats<0><<<256, 256, 0, stream>>>(qkv, g1, b1, g2, b2, scaleA, shiftA);
    k_gram<<<4096, 64, 0, stream>>>(qkv, scaleA, shiftA, Rq, Rk, TqT, TkT, accS);
    k_sfin<<<1, 32, 0, stream>>>(accS, gs, bs, scaleS, shiftS);
    k_attn<<<4096, 256, 0, stream>>>(qkv, scaleA, shiftA, relT, scaleS, shiftS, so);
    k_chstats<1><<<256, 256, 0, stream>>>(so, go, bo, nullptr, nullptr, scaleF, shiftF);
    k_out<<<512, 256, 0, stream>>>(so, scaleF, shiftF, out);
}

// Round 10
// 398.921 us; speedup vs baseline: 1.5293x; 1.5293x over previous
//
#include <hip/hip_runtime.h>
#include <hip/hip_fp16.h>
#include <math.h>

#define B_TOT 512
#define CQKV  256
#define CIN   128
#define HLEN  128

static constexpr float F_QR = 0.3f, F_KR = 0.3f, F_SV = 0.5f, F_SVE = 0.3f;
static constexpr float EPS = 1e-5f;

typedef __attribute__((ext_vector_type(8))) short short8v;
typedef __attribute__((ext_vector_type(8))) _Float16 half8v;
typedef __attribute__((ext_vector_type(4))) float float4v;

__device__ __forceinline__ unsigned short f2bf(float f) {
    unsigned u = __float_as_uint(f);
    unsigned r = u + 0x7fffu + ((u >> 16) & 1u);
    return (unsigned short)(r >> 16);
}
__device__ __forceinline__ unsigned short f2h(float f) {
    return __half_as_ushort(__float2half(f));
}

// ---------------------------------------------------------------------------
// Kernel 1 (MFMA): qkv[b][o][h] = sum_c w[o][c] * x[n][c][w][h]
// + fused per-channel raw stats (sum, sumsq) -> accA (BN1/BN2 input).
// ---------------------------------------------------------------------------
__global__ __launch_bounds__(256, 3) void k_qkv(const float* __restrict__ x,
                                                const float* __restrict__ w,
                                                float* __restrict__ qkv,
                                                double* __restrict__ accA) {
    __shared__ unsigned short As[64][136];
    __shared__ unsigned short Xs[256][64];
    __shared__ float wsum[64][2];
    int bid = blockIdx.x;
    int n   = bid >> 7;
    int sub = bid & 127;
    int mt  = sub >> 2;
    int ot  = sub & 3;
    int m0  = mt << 8;
    int o0  = ot << 6;
    int t   = threadIdx.x;

    if (t < 64) { wsum[t][0] = 0.f; wsum[t][1] = 0.f; }

#pragma unroll
    for (int it = 0; it < 8; ++it) {
        int idx = it * 256 + t;
        int o = idx >> 5, c4 = (idx & 31) << 2;
        float4 wv = *(const float4*)(w + (size_t)(o0 + o) * CIN + c4);
        As[o][c4 + 0] = f2bf(wv.x);
        As[o][c4 + 1] = f2bf(wv.y);
        As[o][c4 + 2] = f2bf(wv.z);
        As[o][c4 + 3] = f2bf(wv.w);
    }

    const float* xn = x + (size_t)n * CIN * 8192 + m0;

    int wv_ = t >> 6, l = t & 63;
    int lr = l & 15, lh = l >> 4;
    int mw = wv_ << 6;

    float4v acc[4][4];
#pragma unroll
    for (int a = 0; a < 4; ++a)
#pragma unroll
        for (int b2 = 0; b2 < 4; ++b2) acc[a][b2] = (float4v){0.f, 0.f, 0.f, 0.f};

    for (int s = 0; s < 2; ++s) {
        int c0 = s << 6;
        __syncthreads();
#pragma unroll
        for (int it = 0; it < 16; ++it) {
            int c  = (it << 2) + (t >> 6);
            int m4 = (t & 63) << 2;
            float4 xv = *(const float4*)(xn + (size_t)(c0 + c) * 8192 + m4);
            float vals[4] = {xv.x, xv.y, xv.z, xv.w};
#pragma unroll
            for (int j = 0; j < 4; ++j) {
                int m = m4 + j;
                int cs = (((c >> 3) ^ ((m >> 2) & 7)) << 3) | (c & 7);
                Xs[m][cs] = f2bf(vals[j]);
            }
        }
        __syncthreads();
#pragma unroll
        for (int ks = 0; ks < 2; ++ks) {
            short8v af[4], bf[4];
#pragma unroll
            for (int a = 0; a < 4; ++a)
                af[a] = *(const short8v*)&As[a * 16 + lr][c0 + ks * 32 + lh * 8];
#pragma unroll
            for (int b2 = 0; b2 < 4; ++b2) {
                int m  = mw + b2 * 16 + lr;
                int cb = (ks * 4 + lh) ^ ((m >> 2) & 7);
                bf[b2] = *(const short8v*)&Xs[m][cb << 3];
            }
#pragma unroll
            for (int a = 0; a < 4; ++a)
#pragma unroll
                for (int b2 = 0; b2 < 4; ++b2)
                    acc[a][b2] = __builtin_amdgcn_mfma_f32_16x16x32_bf16(
                        af[a], bf[b2], acc[a][b2], 0, 0, 0);
        }
    }

#pragma unroll
    for (int a = 0; a < 4; ++a) {
#pragma unroll
        for (int b2 = 0; b2 < 4; ++b2) {
            int m  = m0 + mw + b2 * 16 + lr;
            int bb = n * 64 + (m >> 7);
            int h  = m & 127;
#pragma unroll
            for (int r = 0; r < 4; ++r) {
                int o = o0 + a * 16 + lh * 4 + r;
                qkv[((size_t)bb * CQKV + o) * HLEN + h] = acc[a][b2][r];
            }
        }
    }

    // fused raw-channel stats: reduce this block's 64ch x 256m tile
#pragma unroll
    for (int a = 0; a < 4; ++a) {
#pragma unroll
        for (int r = 0; r < 4; ++r) {
            float s = 0.f, ss = 0.f;
#pragma unroll
            for (int b2 = 0; b2 < 4; ++b2) {
                float v = acc[a][b2][r];
                s += v; ss += v * v;
            }
#pragma unroll
            for (int off = 1; off < 16; off <<= 1) {
                s  += __shfl_xor(s, off);
                ss += __shfl_xor(ss, off);
            }
            if (lr == 0) {
                int ol = a * 16 + lh * 4 + r;
                atomicAdd(&wsum[ol][0], s);
                atomicAdd(&wsum[ol][1], ss);
            }
        }
    }
    __syncthreads();
    if (t < 64) {
        atomicAdd(&accA[(size_t)(o0 + t) * 2 + 0], (double)wsum[t][0]);
        atomicAdd(&accA[(size_t)(o0 + t) * 2 + 1], (double)wsum[t][1]);
    }
}

// ---------------------------------------------------------------------------
// Finalize fused double-BN affine for qkv channels.
// ---------------------------------------------------------------------------
__global__ void k_finA(const double* __restrict__ accA,
                       const float* __restrict__ g1, const float* __restrict__ g2,
                       const float* __restrict__ b2,
                       float* __restrict__ scaleA, float* __restrict__ shiftA) {
    int o = threadIdx.x;
    double cnt  = 65536.0;
    double mean = accA[o * 2] / cnt;
    double var  = accA[o * 2 + 1] / cnt - mean * mean;
    float r1 = rsqrtf((float)var + EPS);
    float v2 = g1[o] * g1[o] * (float)var * r1 * r1;
    float sc = g1[o] * g2[o] * r1 * rsqrtf(v2 + EPS);
    scaleA[o] = sc;
    shiftA[o] = b2[o] - (float)mean * sc;
}

// ---------------------------------------------------------------------------
// Finalize single BN affine for so channels.
// ---------------------------------------------------------------------------
__global__ void k_finF(const double* __restrict__ accF,
                       const float* __restrict__ go, const float* __restrict__ bo,
                       float* __restrict__ scaleF, float* __restrict__ shiftF) {
    int o = threadIdx.x;
    double cnt  = 65536.0;
    double mean = accF[o * 2] / cnt;
    double var  = accF[o * 2 + 1] / cnt - mean * mean;
    float sc = go[o] * rsqrtf((float)var + EPS);
    scaleF[o] = sc;
    shiftF[o] = bo[o] - (float)mean * sc;
}

// ---------------------------------------------------------------------------
// Tables for analytic score stats (f32, for k_gram).
// ---------------------------------------------------------------------------
__global__ __launch_bounds__(128) void k_tables(const float* __restrict__ rel,
                                                float* __restrict__ Rq, float* __restrict__ Rk,
                                                float* __restrict__ TqT, float* __restrict__ TkT) {
    int bid = blockIdx.x;      // 0..127
    int i = threadIdx.x;       // 0..127
    int p = bid & 63;
    int c = p >> 3, c2 = p & 7;
    const float* ra = (bid < 64) ? (rel + c * 255)  : (rel + (8 + c) * 255);
    const float* rb = (bid < 64) ? (rel + c2 * 255) : (rel + (8 + c2) * 255);
    float tacc = 0.f;
    for (int kk = 0; kk < 128; ++kk) tacc = fmaf(ra[i + kk], rb[i + kk], tacc);
    if (bid < 64) TqT[i * 64 + p] = tacc; else TkT[i * 64 + p] = tacc;
    if (c2 == 0) {
        float racc = 0.f;
        for (int kk = 0; kk < 128; ++kk) racc += ra[i + kk];
        if (bid < 64) Rq[c * 128 + i] = racc; else Rk[c * 128 + i] = racc;
    }
}

// ---------------------------------------------------------------------------
// Analytic score stats per (b,g).
// ---------------------------------------------------------------------------
__global__ __launch_bounds__(64) void k_gram(const float* __restrict__ qkv,
                                             const float* __restrict__ scaleA,
                                             const float* __restrict__ shiftA,
                                             const float* __restrict__ Rq,
                                             const float* __restrict__ Rk,
                                             const float* __restrict__ TqT,
                                             const float* __restrict__ TkT,
                                             double* __restrict__ accS) {
    __shared__ float qs[8][132], ks[8][132];
    int blk = blockIdx.x, b = blk >> 3, g = blk & 7;
    int t = threadIdx.x;
    for (int idx = t; idx < 2048; idx += 64) {
        int cc = idx >> 7, h = idx & 127, o = g * 32 + cc;
        float v = qkv[((size_t)b * CQKV + o) * HLEN + h] * scaleA[o] + shiftA[o];
        if (cc < 8) qs[cc][h] = v; else ks[cc - 8][h] = v;
    }
    __syncthreads();
    int c = t >> 3, c2 = t & 7;
    float gq = 0, gk = 0, tq = 0, tk = 0;
    for (int i = 0; i < 128; ++i) {
        float a = qs[c][i] * qs[c2][i];
        float e = ks[c][i] * ks[c2][i];
        gq += a; gk += e;
        tq = fmaf(a, TqT[i * 64 + t], tq);
        tk = fmaf(e, TkT[i * 64 + t], tk);
    }
    float ssqk = gq * gk;
    float sqr = 0, skr = 0;
    float sq8[8], sk8[8];
#pragma unroll
    for (int c3 = 0; c3 < 8; ++c3) {
        float q0 = qs[c3][t], q1 = qs[c3][t + 64];
        float k0 = ks[c3][t], k1 = ks[c3][t + 64];
        sq8[c3] = q0 + q1; sk8[c3] = k0 + k1;
        sqr = fmaf(q0, Rq[c3 * 128 + t], sqr);
        sqr = fmaf(q1, Rq[c3 * 128 + t + 64], sqr);
        skr = fmaf(k0, Rk[c3 * 128 + t], skr);
        skr = fmaf(k1, Rk[c3 * 128 + t + 64], skr);
    }
#pragma unroll
    for (int off = 1; off < 64; off <<= 1) {
        ssqk += __shfl_xor(ssqk, off);
        tq   += __shfl_xor(tq, off);
        tk   += __shfl_xor(tk, off);
        sqr  += __shfl_xor(sqr, off);
        skr  += __shfl_xor(skr, off);
#pragma unroll
        for (int c3 = 0; c3 < 8; ++c3) {
            sq8[c3] += __shfl_xor(sq8[c3], off);
            sk8[c3] += __shfl_xor(sk8[c3], off);
        }
    }
    if (t == 0) {
        float sqk = 0;
#pragma unroll
        for (int c3 = 0; c3 < 8; ++c3) sqk += sq8[c3] * sk8[c3];
        atomicAdd(&accS[g * 2 + 0], (double)sqk);
        atomicAdd(&accS[g * 2 + 1], (double)ssqk);
        atomicAdd(&accS[(8 + g) * 2 + 0], (double)(F_QR * sqr));
        atomicAdd(&accS[(8 + g) * 2 + 1], (double)(F_QR * F_QR * tq));
        atomicAdd(&accS[(16 + g) * 2 + 0], (double)(F_KR * skr));
        atomicAdd(&accS[(16 + g) * 2 + 1], (double)(F_KR * F_KR * tk));
    }
}

__global__ void k_sfin(const double* __restrict__ accS,
                       const float* __restrict__ gs, const float* __restrict__ bs,
                       float* __restrict__ scaleS, float* __restrict__ shiftS) {
    int c = threadIdx.x;
    if (c < 24) {
        double cnt  = 512.0 * 128.0 * 128.0;
        double mean = accS[c * 2] / cnt;
        double var  = accS[c * 2 + 1] / cnt - mean * mean;
        float sc = gs[c] * rsqrtf((float)var + EPS);
        scaleS[c] = sc;
        shiftS[c] = bs[c] - (float)mean * sc;
    }
}

// ---------------------------------------------------------------------------
// Attention (round-8 base: f16 packed math, LDS rel tables) +
//  - half2-domain score combine (one collapse instead of three)
//  - Pl written as b128 (uint4) stores
//  - fused BN stats of so -> accF (shfl reduces + LDS partials + 32 atomics)
// ---------------------------------------------------------------------------
__global__ __launch_bounds__(256, 4) void k_attn(const float* __restrict__ qkv,
                                                 const float* __restrict__ scaleA,
                                                 const float* __restrict__ shiftA,
                                                 const float* __restrict__ rel,
                                                 const float* __restrict__ scaleS,
                                                 const float* __restrict__ shiftS,
                                                 float* __restrict__ so,
                                                 double* __restrict__ accF) {
    __shared__ unsigned short qT[128][8];
    __shared__ unsigned short kF[128][8];
    __shared__ unsigned short vB[16][136];
    __shared__ unsigned short rqT[255][8];
    __shared__ unsigned short rkT[255][8];
    __shared__ unsigned short rvA[255][8];
    __shared__ unsigned short rvB[255][8];
    __shared__ unsigned short Pl[128][136];
    __shared__ float accL[32][2];
    int blk = blockIdx.x, b = blk >> 3, g = blk & 7;
    int t = threadIdx.x;
    if (t < 32) { accL[t][0] = 0.f; accL[t][1] = 0.f; }
    for (int idx = t; idx < 32 * 128; idx += 256) {
        int cc = idx >> 7, h = idx & 127, o = g * 32 + cc;
        float v = qkv[((size_t)b * CQKV + o) * HLEN + h] * scaleA[o] + shiftA[o];
        if (cc < 8)       qT[h][cc] = f2h(v);
        else if (cc < 16) kF[h][cc - 8] = f2h(v);
        else              vB[cc - 16][h] = f2h(v);
    }
    for (int idx = t; idx < 32 * 255; idx += 256) {
        int r = idx / 255, d = idx - r * 255;
        unsigned short us = f2h(rel[r * 255 + d]);
        if (r < 8)       rqT[d][r] = us;
        else if (r < 16) rkT[d][r - 8] = us;
        else if (r < 24) rvA[d][r - 16] = us;
        else             rvB[d][r - 24] = us;
    }
    __syncthreads();

    float cA = scaleS[g], cB = F_QR * scaleS[8 + g], cC = F_KR * scaleS[16 + g];
    float shsum = shiftS[g] + shiftS[8 + g] + shiftS[16 + g];
    __half2 cA2 = __float2half2_rn(cA);
    __half2 cB2 = __float2half2_rn(cB);
    __half2 cC2 = __float2half2_rn(cC);

    int i = t >> 1, j0 = (t & 1) << 6;
    __half2 q2[4];
    {
        uint4 qv = *(const uint4*)&qT[i][0];
        q2[0] = *(__half2*)&qv.x; q2[1] = *(__half2*)&qv.y;
        q2[2] = *(__half2*)&qv.z; q2[3] = *(__half2*)&qv.w;
    }

    float p[64];
    float rowmax = -1e30f;
#pragma unroll
    for (int jj = 0; jj < 64; ++jj) {
        int j = j0 + jj;
        uint4 kv = *(const uint4*)&kF[j][0];
        uint4 rq = *(const uint4*)&rqT[i - j + 127][0];
        uint4 rk = *(const uint4*)&rkT[j - i + 127][0];
        __half2* k2  = (__half2*)&kv;
        __half2* rq2 = (__half2*)&rq;
        __half2* rk2 = (__half2*)&rk;
        __half2 hqk = __hfma2(q2[0], k2[0], __hfma2(q2[1], k2[1],
                      __hfma2(q2[2], k2[2], __hmul2(q2[3], k2[3]))));
        __half2 hqr = __hfma2(q2[0], rq2[0], __hfma2(q2[1], rq2[1],
                      __hfma2(q2[2], rq2[2], __hmul2(q2[3], rq2[3]))));
        __half2 hkr = __hfma2(k2[0], rk2[0], __hfma2(k2[1], rk2[1],
                      __hfma2(k2[2], rk2[2], __hmul2(k2[3], rk2[3]))));
        __half2 s2 = __hfma2(hqk, cA2, __hfma2(hqr, cB2, __hmul2(hkr, cC2)));
        float s = __low2float(s2) + __high2float(s2) + shsum;
        p[jj] = s;
        rowmax = fmaxf(rowmax, s);
    }
    rowmax = fmaxf(rowmax, __shfl_xor(rowmax, 1));
    float rsum = 0.f;
#pragma unroll
    for (int jj = 0; jj < 64; ++jj) {
        float e = __expf(p[jj] - rowmax);
        p[jj] = e;
        rsum += e;
    }
    rsum += __shfl_xor(rsum, 1);
    float rn = 1.f / rsum;

    // ---- write P*rn as f16 to LDS (b128 stores) ----
#pragma unroll
    for (int k8 = 0; k8 < 8; ++k8) {
        uint4 w4;
        unsigned* wp = (unsigned*)&w4;
#pragma unroll
        for (int e = 0; e < 4; ++e) {
            __half2 h2 = __floats2half2_rn(p[8 * k8 + 2 * e] * rn,
                                           p[8 * k8 + 2 * e + 1] * rn);
            wp[e] = *(unsigned*)&h2;
        }
        *(uint4*)&Pl[i][j0 + 8 * k8] = w4;
    }

    // ---- sve = P (*) v_emb: packed f16 MACs ----
    __half2 acc2[8];
#pragma unroll
    for (int m = 0; m < 8; ++m) acc2[m] = __floats2half2_rn(0.f, 0.f);
#pragma unroll
    for (int jj = 0; jj < 64; ++jj) {
        int j = j0 + jj;
        int d = i - j + 127;
        __half2 p2 = __float2half2_rn(p[jj]);
        uint4 ra = *(const uint4*)&rvA[d][0];
        uint4 rb = *(const uint4*)&rvB[d][0];
        __half2* ra2 = (__half2*)&ra;
        __half2* rb2 = (__half2*)&rb;
        acc2[0] = __hfma2(p2, ra2[0], acc2[0]);
        acc2[1] = __hfma2(p2, ra2[1], acc2[1]);
        acc2[2] = __hfma2(p2, ra2[2], acc2[2]);
        acc2[3] = __hfma2(p2, ra2[3], acc2[3]);
        acc2[4] = __hfma2(p2, rb2[0], acc2[4]);
        acc2[5] = __hfma2(p2, rb2[1], acc2[5]);
        acc2[6] = __hfma2(p2, rb2[2], acc2[6]);
        acc2[7] = __hfma2(p2, rb2[3], acc2[7]);
    }
    float a1[16];
#pragma unroll
    for (int m = 0; m < 8; ++m) {
        a1[2 * m]     = __low2float(acc2[m]);
        a1[2 * m + 1] = __high2float(acc2[m]);
    }
#pragma unroll
    for (int c = 0; c < 16; ++c) a1[c] += __shfl_xor(a1[c], 1);
    {
        int cbase = (t & 1) * 8;
        float sce = F_SVE * rn;
        float* sop = so + ((size_t)b * CQKV + g * 32) * HLEN + i;
        float svp[8], ssvp[8];
#pragma unroll
        for (int c8 = 0; c8 < 8; ++c8) {
            int c = cbase + c8;
            float v = a1[c] * sce;
            sop[(size_t)(2 * c + 1) * HLEN] = v;
            svp[c8] = v; ssvp[c8] = v * v;
        }
        // stats: reduce over same-parity lanes (i dimension) of this wave
#pragma unroll
        for (int off = 2; off < 64; off <<= 1) {
#pragma unroll
            for (int c8 = 0; c8 < 8; ++c8) {
                svp[c8]  += __shfl_xor(svp[c8], off);
                ssvp[c8] += __shfl_xor(ssvp[c8], off);
            }
        }
        if ((t & 62) == 0) {        // lanes 0,1 of each wave
#pragma unroll
            for (int c8 = 0; c8 < 8; ++c8) {
                int c = cbase + c8;
                atomicAdd(&accL[2 * c + 1][0], svp[c8]);
                atomicAdd(&accL[2 * c + 1][1], ssvp[c8]);
            }
        }
    }

    __syncthreads();

    // ---- sv via MFMA (f16) + fused stats ----
    {
        int w = t >> 6, l = t & 63;
        int lr = l & 15, lh = l >> 4;
        float s0 = 0.f, ss0 = 0.f;
#pragma unroll
        for (int it = 0; it < 2; ++it) {
            int itile = w * 2 + it;
            float4v acc = {0.f, 0.f, 0.f, 0.f};
#pragma unroll
            for (int ks = 0; ks < 4; ++ks) {
                half8v af = *(const half8v*)&Pl[itile * 16 + lr][ks * 32 + lh * 8];
                half8v bf = *(const half8v*)&vB[lr][ks * 32 + lh * 8];
                acc = __builtin_amdgcn_mfma_f32_16x16x32_f16(af, bf, acc, 0, 0, 0);
            }
            int oc = g * 32 + 2 * lr;                       // even slot = sv
            float* sop = so + ((size_t)b * CQKV + oc) * HLEN + itile * 16 + lh * 4;
            float4 outv;
            outv.x = acc[0] * F_SV; outv.y = acc[1] * F_SV;
            outv.z = acc[2] * F_SV; outv.w = acc[3] * F_SV;
            *(float4*)sop = outv;
            s0  += outv.x + outv.y + outv.z + outv.w;
            ss0 += outv.x * outv.x + outv.y * outv.y + outv.z * outv.z + outv.w * outv.w;
        }
        s0  += __shfl_xor(s0, 16);  s0  += __shfl_xor(s0, 32);
        ss0 += __shfl_xor(ss0, 16); ss0 += __shfl_xor(ss0, 32);
        if (lh == 0) {
            atomicAdd(&accL[2 * lr][0], s0);
            atomicAdd(&accL[2 * lr][1], ss0);
        }
    }
    __syncthreads();
    if (t < 32) {
        int o = g * 32 + t;
        atomicAdd(&accF[(size_t)o * 2 + 0], (double)accL[t][0]);
        atomicAdd(&accF[(size_t)o * 2 + 1], (double)accL[t][1]);
    }
}

// ---------------------------------------------------------------------------
// Final affine + pair-sum + transpose
// ---------------------------------------------------------------------------
__global__ __launch_bounds__(256) void k_out(const float* __restrict__ so,
                                             const float* __restrict__ scale,
                                             const float* __restrict__ shift,
                                             float* __restrict__ out) {
    int b = blockIdx.x, n = b >> 6, wi = b & 63;
    int t = threadIdx.x, h = t & 127, half = t >> 7;
    for (int oc = half * 64; oc < half * 64 + 64; ++oc) {
        float v0 = so[((size_t)b * CQKV + 2 * oc) * HLEN + h] * scale[2 * oc] + shift[2 * oc];
        float v1 = so[((size_t)b * CQKV + 2 * oc + 1) * HLEN + h] * scale[2 * oc + 1] + shift[2 * oc + 1];
        out[(((size_t)n * 128 + oc) * 64 + wi) * HLEN + h] = v0 + v1;
    }
}

extern "C" void kernel_launch(void* const* d_in, const int* in_sizes, int n_in,
                              void* d_out, int out_size, void* d_ws, size_t ws_size,
                              hipStream_t stream) {
    const float* x   = (const float*)d_in[0];
    const float* w   = (const float*)d_in[1];
    const float* g1  = (const float*)d_in[2];
    const float* b1  = (const float*)d_in[3];
    const float* g2  = (const float*)d_in[4];
    const float* b2  = (const float*)d_in[5];
    const float* gs  = (const float*)d_in[6];
    const float* bs  = (const float*)d_in[7];
    const float* go  = (const float*)d_in[8];
    const float* bo  = (const float*)d_in[9];
    const float* rel = (const float*)d_in[10];
    float* out = (float*)d_out;

    float*  qkv    = (float*)d_ws;                      // 16,777,216 f
    float*  so     = qkv + (size_t)16777216;            // 16,777,216 f
    double* accA   = (double*)(so + (size_t)16777216);  // 512 d
    double* accS   = accA + 512;                        // 48 d
    double* accF   = accS + 48;                         // 512 d
    float*  scaleA = (float*)(accF + 512);
    float*  shiftA = scaleA + 256;
    float*  scaleS = shiftA + 256;                      // 24
    float*  shiftS = scaleS + 24;
    float*  scaleF = shiftS + 24;                       // 256
    float*  shiftF = scaleF + 256;
    float*  Rq     = shiftF + 256;                      // 1024
    float*  Rk     = Rq + 1024;                         // 1024
    float*  TqT    = Rk + 1024;                         // 8192
    float*  TkT    = TqT + 8192;                        // 8192

    hipMemsetAsync(accA, 0, (512 + 48 + 512) * sizeof(double), stream);

    k_qkv<<<1024, 256, 0, stream>>>(x, w, qkv, accA);
    k_tables<<<128, 128, 0, stream>>>(rel, Rq, Rk, TqT, TkT);
    k_finA<<<1, 256, 0, stream>>>(accA, g1, g2, b2, scaleA, shiftA);
    k_gram<<<4096, 64, 0, stream>>>(qkv, scaleA, shiftA, Rq, Rk, TqT, TkT, accS);
    k_sfin<<<1, 32, 0, stream>>>(accS, gs, bs, scaleS, shiftS);
    k_attn<<<4096, 256, 0, stream>>>(qkv, scaleA, shiftA, rel, scaleS, shiftS, so, accF);
    k_finF<<<1, 256, 0, stream>>>(accF, go, bo, scaleF, shiftF);
    k_out<<<512, 256, 0, stream>>>(so, scaleF, shiftF, out);
}

// Round 11
// 344.918 us; speedup vs baseline: 1.7688x; 1.1566x over previous
//
#include <hip/hip_runtime.h>
#include <hip/hip_fp16.h>
#include <math.h>

#define B_TOT 512
#define CQKV  256
#define CIN   128
#define HLEN  128

static constexpr float F_QR = 0.3f, F_KR = 0.3f, F_SV = 0.5f, F_SVE = 0.3f;
static constexpr float EPS = 1e-5f;

typedef __attribute__((ext_vector_type(8))) short short8v;
typedef __attribute__((ext_vector_type(8))) _Float16 half8v;
typedef __attribute__((ext_vector_type(2))) _Float16 half2v;
typedef __attribute__((ext_vector_type(4))) float float4v;

#if __has_builtin(__builtin_amdgcn_fdot2)
#define HAVE_FDOT2 1
#endif

__device__ __forceinline__ unsigned short f2bf(float f) {
    unsigned u = __float_as_uint(f);
    unsigned r = u + 0x7fffu + ((u >> 16) & 1u);
    return (unsigned short)(r >> 16);
}
__device__ __forceinline__ unsigned short f2h(float f) {
    return __half_as_ushort(__float2half(f));
}

// ---------------------------------------------------------------------------
// Kernel 1 (MFMA): qkv[b][o][h] = sum_c w[o][c] * x[n][c][w][h]
// + fused per-channel raw stats (sum, sumsq) -> accA.
// ---------------------------------------------------------------------------
__global__ __launch_bounds__(256, 3) void k_qkv(const float* __restrict__ x,
                                                const float* __restrict__ w,
                                                float* __restrict__ qkv,
                                                double* __restrict__ accA) {
    __shared__ unsigned short As[64][136];
    __shared__ unsigned short Xs[256][64];
    __shared__ float wsum[64][2];
    int bid = blockIdx.x;
    int n   = bid >> 7;
    int sub = bid & 127;
    int mt  = sub >> 2;
    int ot  = sub & 3;
    int m0  = mt << 8;
    int o0  = ot << 6;
    int t   = threadIdx.x;

    if (t < 64) { wsum[t][0] = 0.f; wsum[t][1] = 0.f; }

#pragma unroll
    for (int it = 0; it < 8; ++it) {
        int idx = it * 256 + t;
        int o = idx >> 5, c4 = (idx & 31) << 2;
        float4 wv = *(const float4*)(w + (size_t)(o0 + o) * CIN + c4);
        As[o][c4 + 0] = f2bf(wv.x);
        As[o][c4 + 1] = f2bf(wv.y);
        As[o][c4 + 2] = f2bf(wv.z);
        As[o][c4 + 3] = f2bf(wv.w);
    }

    const float* xn = x + (size_t)n * CIN * 8192 + m0;

    int wv_ = t >> 6, l = t & 63;
    int lr = l & 15, lh = l >> 4;
    int mw = wv_ << 6;

    float4v acc[4][4];
#pragma unroll
    for (int a = 0; a < 4; ++a)
#pragma unroll
        for (int b2 = 0; b2 < 4; ++b2) acc[a][b2] = (float4v){0.f, 0.f, 0.f, 0.f};

    for (int s = 0; s < 2; ++s) {
        int c0 = s << 6;
        __syncthreads();
#pragma unroll
        for (int it = 0; it < 16; ++it) {
            int c  = (it << 2) + (t >> 6);
            int m4 = (t & 63) << 2;
            float4 xv = *(const float4*)(xn + (size_t)(c0 + c) * 8192 + m4);
            float vals[4] = {xv.x, xv.y, xv.z, xv.w};
#pragma unroll
            for (int j = 0; j < 4; ++j) {
                int m = m4 + j;
                int cs = (((c >> 3) ^ ((m >> 2) & 7)) << 3) | (c & 7);
                Xs[m][cs] = f2bf(vals[j]);
            }
        }
        __syncthreads();
#pragma unroll
        for (int ks = 0; ks < 2; ++ks) {
            short8v af[4], bf[4];
#pragma unroll
            for (int a = 0; a < 4; ++a)
                af[a] = *(const short8v*)&As[a * 16 + lr][c0 + ks * 32 + lh * 8];
#pragma unroll
            for (int b2 = 0; b2 < 4; ++b2) {
                int m  = mw + b2 * 16 + lr;
                int cb = (ks * 4 + lh) ^ ((m >> 2) & 7);
                bf[b2] = *(const short8v*)&Xs[m][cb << 3];
            }
#pragma unroll
            for (int a = 0; a < 4; ++a)
#pragma unroll
                for (int b2 = 0; b2 < 4; ++b2)
                    acc[a][b2] = __builtin_amdgcn_mfma_f32_16x16x32_bf16(
                        af[a], bf[b2], acc[a][b2], 0, 0, 0);
        }
    }

#pragma unroll
    for (int a = 0; a < 4; ++a) {
#pragma unroll
        for (int b2 = 0; b2 < 4; ++b2) {
            int m  = m0 + mw + b2 * 16 + lr;
            int bb = n * 64 + (m >> 7);
            int h  = m & 127;
#pragma unroll
            for (int r = 0; r < 4; ++r) {
                int o = o0 + a * 16 + lh * 4 + r;
                qkv[((size_t)bb * CQKV + o) * HLEN + h] = acc[a][b2][r];
            }
        }
    }

    // fused raw-channel stats
#pragma unroll
    for (int a = 0; a < 4; ++a) {
#pragma unroll
        for (int r = 0; r < 4; ++r) {
            float s = 0.f, ss = 0.f;
#pragma unroll
            for (int b2 = 0; b2 < 4; ++b2) {
                float v = acc[a][b2][r];
                s += v; ss += v * v;
            }
#pragma unroll
            for (int off = 1; off < 16; off <<= 1) {
                s  += __shfl_xor(s, off);
                ss += __shfl_xor(ss, off);
            }
            if (lr == 0) {
                int ol = a * 16 + lh * 4 + r;
                atomicAdd(&wsum[ol][0], s);
                atomicAdd(&wsum[ol][1], ss);
            }
        }
    }
    __syncthreads();
    if (t < 64) {
        atomicAdd(&accA[(size_t)(o0 + t) * 2 + 0], (double)wsum[t][0]);
        atomicAdd(&accA[(size_t)(o0 + t) * 2 + 1], (double)wsum[t][1]);
    }
}

__global__ void k_finA(const double* __restrict__ accA,
                       const float* __restrict__ g1, const float* __restrict__ g2,
                       const float* __restrict__ b2,
                       float* __restrict__ scaleA, float* __restrict__ shiftA) {
    int o = threadIdx.x;
    double cnt  = 65536.0;
    double mean = accA[o * 2] / cnt;
    double var  = accA[o * 2 + 1] / cnt - mean * mean;
    float r1 = rsqrtf((float)var + EPS);
    float v2 = g1[o] * g1[o] * (float)var * r1 * r1;
    float sc = g1[o] * g2[o] * r1 * rsqrtf(v2 + EPS);
    scaleA[o] = sc;
    shiftA[o] = b2[o] - (float)mean * sc;
}

__global__ void k_finF(const double* __restrict__ accF,
                       const float* __restrict__ go, const float* __restrict__ bo,
                       float* __restrict__ scaleF, float* __restrict__ shiftF) {
    int o = threadIdx.x;
    double cnt  = 65536.0;
    double mean = accF[o * 2] / cnt;
    double var  = accF[o * 2 + 1] / cnt - mean * mean;
    float sc = go[o] * rsqrtf((float)var + EPS);
    scaleF[o] = sc;
    shiftF[o] = bo[o] - (float)mean * sc;
}

// ---------------------------------------------------------------------------
// Tables for analytic score stats (f32, for k_gram).
// ---------------------------------------------------------------------------
__global__ __launch_bounds__(128) void k_tables(const float* __restrict__ rel,
                                                float* __restrict__ Rq, float* __restrict__ Rk,
                                                float* __restrict__ TqT, float* __restrict__ TkT) {
    int bid = blockIdx.x;      // 0..127
    int i = threadIdx.x;       // 0..127
    int p = bid & 63;
    int c = p >> 3, c2 = p & 7;
    const float* ra = (bid < 64) ? (rel + c * 255)  : (rel + (8 + c) * 255);
    const float* rb = (bid < 64) ? (rel + c2 * 255) : (rel + (8 + c2) * 255);
    float tacc = 0.f;
    for (int kk = 0; kk < 128; ++kk) tacc = fmaf(ra[i + kk], rb[i + kk], tacc);
    if (bid < 64) TqT[i * 64 + p] = tacc; else TkT[i * 64 + p] = tacc;
    if (c2 == 0) {
        float racc = 0.f;
        for (int kk = 0; kk < 128; ++kk) racc += ra[i + kk];
        if (bid < 64) Rq[c * 128 + i] = racc; else Rk[c * 128 + i] = racc;
    }
}

// ---------------------------------------------------------------------------
// Analytic score stats per (b,g) — 256 threads (4x parallel i-loop).
// ---------------------------------------------------------------------------
__global__ __launch_bounds__(256) void k_gram(const float* __restrict__ qkv,
                                              const float* __restrict__ scaleA,
                                              const float* __restrict__ shiftA,
                                              const float* __restrict__ Rq,
                                              const float* __restrict__ Rk,
                                              const float* __restrict__ TqT,
                                              const float* __restrict__ TkT,
                                              double* __restrict__ accS) {
    __shared__ float qs[8][132], ks[8][132];
    __shared__ float redA[4][64][4];
    __shared__ float redB[2][18];
    __shared__ float redC[3];
    int blk = blockIdx.x, b = blk >> 3, g = blk & 7;
    int t = threadIdx.x;
    for (int idx = t; idx < 2048; idx += 256) {
        int cc = idx >> 7, h = idx & 127, o = g * 32 + cc;
        float v = qkv[((size_t)b * CQKV + o) * HLEN + h] * scaleA[o] + shiftA[o];
        if (cc < 8) qs[cc][h] = v; else ks[cc - 8][h] = v;
    }
    __syncthreads();
    int lane = t & 63, wv = t >> 6;
    int c = lane >> 3, c2 = lane & 7;
    float gq = 0, gk = 0, tq = 0, tk = 0;
#pragma unroll 4
    for (int ii = 0; ii < 32; ++ii) {
        int i = wv * 32 + ii;
        float a = qs[c][i] * qs[c2][i];
        float e = ks[c][i] * ks[c2][i];
        gq += a; gk += e;
        tq = fmaf(a, TqT[i * 64 + lane], tq);
        tk = fmaf(e, TkT[i * 64 + lane], tk);
    }
    redA[wv][lane][0] = gq; redA[wv][lane][1] = gk;
    redA[wv][lane][2] = tq; redA[wv][lane][3] = tk;

    // h-indexed sums on waves 0,1
    if (t < 128) {
        int h = t;
        float sqr = 0, skr = 0;
        float sq8l[8], sk8l[8];
#pragma unroll
        for (int c3 = 0; c3 < 8; ++c3) {
            float q0 = qs[c3][h], k0 = ks[c3][h];
            sq8l[c3] = q0; sk8l[c3] = k0;
            sqr = fmaf(q0, Rq[c3 * 128 + h], sqr);
            skr = fmaf(k0, Rk[c3 * 128 + h], skr);
        }
#pragma unroll
        for (int off = 1; off < 64; off <<= 1) {
            sqr += __shfl_xor(sqr, off);
            skr += __shfl_xor(skr, off);
#pragma unroll
            for (int c3 = 0; c3 < 8; ++c3) {
                sq8l[c3] += __shfl_xor(sq8l[c3], off);
                sk8l[c3] += __shfl_xor(sk8l[c3], off);
            }
        }
        if (lane == 0) {
            redB[wv][0] = sqr; redB[wv][1] = skr;
#pragma unroll
            for (int c3 = 0; c3 < 8; ++c3) {
                redB[wv][2 + c3]  = sq8l[c3];
                redB[wv][10 + c3] = sk8l[c3];
            }
        }
    }
    __syncthreads();
    if (t < 64) {
        float Gq = redA[0][t][0] + redA[1][t][0] + redA[2][t][0] + redA[3][t][0];
        float Gk = redA[0][t][1] + redA[1][t][1] + redA[2][t][1] + redA[3][t][1];
        float Tq = redA[0][t][2] + redA[1][t][2] + redA[2][t][2] + redA[3][t][2];
        float Tk = redA[0][t][3] + redA[1][t][3] + redA[2][t][3] + redA[3][t][3];
        float ssqk = Gq * Gk;
#pragma unroll
        for (int off = 1; off < 64; off <<= 1) {
            ssqk += __shfl_xor(ssqk, off);
            Tq   += __shfl_xor(Tq, off);
            Tk   += __shfl_xor(Tk, off);
        }
        if (t == 0) { redC[0] = ssqk; redC[1] = Tq; redC[2] = Tk; }
    }
    __syncthreads();
    if (t == 0) {
        float sqr = redB[0][0] + redB[1][0];
        float skr = redB[0][1] + redB[1][1];
        float sqk = 0;
#pragma unroll
        for (int c3 = 0; c3 < 8; ++c3)
            sqk += (redB[0][2 + c3] + redB[1][2 + c3]) * (redB[0][10 + c3] + redB[1][10 + c3]);
        atomicAdd(&accS[g * 2 + 0], (double)sqk);
        atomicAdd(&accS[g * 2 + 1], (double)redC[0]);
        atomicAdd(&accS[(8 + g) * 2 + 0], (double)(F_QR * sqr));
        atomicAdd(&accS[(8 + g) * 2 + 1], (double)(F_QR * F_QR * redC[1]));
        atomicAdd(&accS[(16 + g) * 2 + 0], (double)(F_KR * skr));
        atomicAdd(&accS[(16 + g) * 2 + 1], (double)(F_KR * F_KR * redC[2]));
    }
}

__global__ void k_sfin(const double* __restrict__ accS,
                       const float* __restrict__ gs, const float* __restrict__ bs,
                       float* __restrict__ scaleS, float* __restrict__ shiftS) {
    int c = threadIdx.x;
    if (c < 24) {
        double cnt  = 512.0 * 128.0 * 128.0;
        double mean = accS[c * 2] / cnt;
        double var  = accS[c * 2 + 1] / cnt - mean * mean;
        float sc = gs[c] * rsqrtf((float)var + EPS);
        scaleS[c] = sc;
        shiftS[c] = bs[c] - (float)mean * sc;
    }
}

// ---------------------------------------------------------------------------
// Attention: round-10 base + (256,2) scheduling headroom + fdot2 score dots
// + vectorized float4 staging. LDS 59.9KB (2 blocks/CU, LDS-capped — the
// (256,4) VGPR cap bought nothing, so free the allocator).
// ---------------------------------------------------------------------------
__global__ __launch_bounds__(256, 2) void k_attn(const float* __restrict__ qkv,
                                                 const float* __restrict__ scaleA,
                                                 const float* __restrict__ shiftA,
                                                 const float* __restrict__ rel,
                                                 const float* __restrict__ scaleS,
                                                 const float* __restrict__ shiftS,
                                                 float* __restrict__ so,
                                                 double* __restrict__ accF) {
    __shared__ unsigned short qT[128][8];
    __shared__ unsigned short kF[128][8];
    __shared__ unsigned short vB[16][136];
    __shared__ unsigned short rqT[255][8];
    __shared__ unsigned short rkT[255][8];
    __shared__ unsigned short rvA[255][8];
    __shared__ unsigned short rvB[255][8];
    __shared__ unsigned short Pl[128][136];
    __shared__ float accL[32][2];
    int blk = blockIdx.x, b = blk >> 3, g = blk & 7;
    int t = threadIdx.x;
    if (t < 32) { accL[t][0] = 0.f; accL[t][1] = 0.f; }

    // ---- staging: qkv via float4 ----
#pragma unroll
    for (int it = 0; it < 4; ++it) {
        int idx = it * 256 + t;
        int cc = idx >> 5;
        int h4 = (idx & 31) << 2;
        int o = g * 32 + cc;
        float4 v4 = *(const float4*)(qkv + ((size_t)b * CQKV + o) * HLEN + h4);
        float sc = scaleA[o], sh = shiftA[o];
        float f0 = fmaf(v4.x, sc, sh), f1 = fmaf(v4.y, sc, sh);
        float f2 = fmaf(v4.z, sc, sh), f3 = fmaf(v4.w, sc, sh);
        if (cc < 8) {
            qT[h4][cc] = f2h(f0); qT[h4 + 1][cc] = f2h(f1);
            qT[h4 + 2][cc] = f2h(f2); qT[h4 + 3][cc] = f2h(f3);
        } else if (cc < 16) {
            kF[h4][cc - 8] = f2h(f0); kF[h4 + 1][cc - 8] = f2h(f1);
            kF[h4 + 2][cc - 8] = f2h(f2); kF[h4 + 3][cc - 8] = f2h(f3);
        } else {
            uint2 pk;
            pk.x = (unsigned)f2h(f0) | ((unsigned)f2h(f1) << 16);
            pk.y = (unsigned)f2h(f2) | ((unsigned)f2h(f3) << 16);
            *(uint2*)&vB[cc - 16][h4] = pk;
        }
    }
    // ---- staging: rel via float4 ----
#pragma unroll
    for (int it = 0; it < 8; ++it) {
        int idx = it * 256 + t;
        if (idx < 2040) {
            float4 v = *(const float4*)(rel + (size_t)idx * 4);
            float vv[4] = {v.x, v.y, v.z, v.w};
#pragma unroll
            for (int e = 0; e < 4; ++e) {
                int lin = idx * 4 + e;
                int r = lin / 255;
                int d = lin - r * 255;
                unsigned short us = f2h(vv[e]);
                if (r < 8)       rqT[d][r] = us;
                else if (r < 16) rkT[d][r - 8] = us;
                else if (r < 24) rvA[d][r - 16] = us;
                else             rvB[d][r - 24] = us;
            }
        }
    }
    __syncthreads();

    float cA = scaleS[g], cB = F_QR * scaleS[8 + g], cC = F_KR * scaleS[16 + g];
    float shsum = shiftS[g] + shiftS[8 + g] + shiftS[16 + g];

    int i = t >> 1, j0 = (t & 1) << 6;
    half2v q2[4];
    {
        uint4 qv = *(const uint4*)&qT[i][0];
        q2[0] = *(half2v*)&qv.x; q2[1] = *(half2v*)&qv.y;
        q2[2] = *(half2v*)&qv.z; q2[3] = *(half2v*)&qv.w;
    }

    float p[64];
    float rowmax = -1e30f;
#pragma unroll
    for (int jj = 0; jj < 64; ++jj) {
        int j = j0 + jj;
        uint4 kv = *(const uint4*)&kF[j][0];
        uint4 rq = *(const uint4*)&rqT[i - j + 127][0];
        uint4 rk = *(const uint4*)&rkT[j - i + 127][0];
        half2v* k2p  = (half2v*)&kv;
        half2v* rq2p = (half2v*)&rq;
        half2v* rk2p = (half2v*)&rk;
#ifdef HAVE_FDOT2
        float qk = __builtin_amdgcn_fdot2(q2[0], k2p[0],
                   __builtin_amdgcn_fdot2(q2[1], k2p[1],
                   __builtin_amdgcn_fdot2(q2[2], k2p[2],
                   __builtin_amdgcn_fdot2(q2[3], k2p[3], 0.f, false), false), false), false);
        float qr = __builtin_amdgcn_fdot2(q2[0], rq2p[0],
                   __builtin_amdgcn_fdot2(q2[1], rq2p[1],
                   __builtin_amdgcn_fdot2(q2[2], rq2p[2],
                   __builtin_amdgcn_fdot2(q2[3], rq2p[3], 0.f, false), false), false), false);
        float kr = __builtin_amdgcn_fdot2(k2p[0], rk2p[0],
                   __builtin_amdgcn_fdot2(k2p[1], rk2p[1],
                   __builtin_amdgcn_fdot2(k2p[2], rk2p[2],
                   __builtin_amdgcn_fdot2(k2p[3], rk2p[3], 0.f, false), false), false), false);
#else
        __half2* k2  = (__half2*)&kv;
        __half2* rq2 = (__half2*)&rq;
        __half2* rk2 = (__half2*)&rk;
        __half2* qh2 = (__half2*)&q2[0];
        __half2 hqk = __hfma2(qh2[0], k2[0], __hfma2(qh2[1], k2[1],
                      __hfma2(qh2[2], k2[2], __hmul2(qh2[3], k2[3]))));
        __half2 hqr = __hfma2(qh2[0], rq2[0], __hfma2(qh2[1], rq2[1],
                      __hfma2(qh2[2], rq2[2], __hmul2(qh2[3], rq2[3]))));
        __half2 hkr = __hfma2(k2[0], rk2[0], __hfma2(k2[1], rk2[1],
                      __hfma2(k2[2], rk2[2], __hmul2(k2[3], rk2[3]))));
        float qk = __low2float(hqk) + __high2float(hqk);
        float qr = __low2float(hqr) + __high2float(hqr);
        float kr = __low2float(hkr) + __high2float(hkr);
#endif
        float s = fmaf(qk, cA, fmaf(qr, cB, fmaf(kr, cC, shsum)));
        p[jj] = s;
        rowmax = fmaxf(rowmax, s);
    }
    rowmax = fmaxf(rowmax, __shfl_xor(rowmax, 1));
    float rsum = 0.f;
#pragma unroll
    for (int jj = 0; jj < 64; ++jj) {
        float e = __expf(p[jj] - rowmax);
        p[jj] = e;
        rsum += e;
    }
    rsum += __shfl_xor(rsum, 1);
    float rn = 1.f / rsum;

    // ---- write P*rn as f16 to LDS (b128 stores) ----
#pragma unroll
    for (int k8 = 0; k8 < 8; ++k8) {
        uint4 w4;
        unsigned* wp = (unsigned*)&w4;
#pragma unroll
        for (int e = 0; e < 4; ++e) {
            __half2 h2 = __floats2half2_rn(p[8 * k8 + 2 * e] * rn,
                                           p[8 * k8 + 2 * e + 1] * rn);
            wp[e] = *(unsigned*)&h2;
        }
        *(uint4*)&Pl[i][j0 + 8 * k8] = w4;
    }

    // ---- sve = P (*) v_emb: packed f16 MACs ----
    __half2 acc2[8];
#pragma unroll
    for (int m = 0; m < 8; ++m) acc2[m] = __floats2half2_rn(0.f, 0.f);
#pragma unroll
    for (int jj = 0; jj < 64; ++jj) {
        int j = j0 + jj;
        int d = i - j + 127;
        __half2 p2 = __float2half2_rn(p[jj]);
        uint4 ra = *(const uint4*)&rvA[d][0];
        uint4 rb = *(const uint4*)&rvB[d][0];
        __half2* ra2 = (__half2*)&ra;
        __half2* rb2 = (__half2*)&rb;
        acc2[0] = __hfma2(p2, ra2[0], acc2[0]);
        acc2[1] = __hfma2(p2, ra2[1], acc2[1]);
        acc2[2] = __hfma2(p2, ra2[2], acc2[2]);
        acc2[3] = __hfma2(p2, ra2[3], acc2[3]);
        acc2[4] = __hfma2(p2, rb2[0], acc2[4]);
        acc2[5] = __hfma2(p2, rb2[1], acc2[5]);
        acc2[6] = __hfma2(p2, rb2[2], acc2[6]);
        acc2[7] = __hfma2(p2, rb2[3], acc2[7]);
    }
    float a1[16];
#pragma unroll
    for (int m = 0; m < 8; ++m) {
        a1[2 * m]     = __low2float(acc2[m]);
        a1[2 * m + 1] = __high2float(acc2[m]);
    }
#pragma unroll
    for (int c = 0; c < 16; ++c) a1[c] += __shfl_xor(a1[c], 1);
    {
        int cbase = (t & 1) * 8;
        float sce = F_SVE * rn;
        float* sop = so + ((size_t)b * CQKV + g * 32) * HLEN + i;
        float svp[8], ssvp[8];
#pragma unroll
        for (int c8 = 0; c8 < 8; ++c8) {
            int c = cbase + c8;
            float v = a1[c] * sce;
            sop[(size_t)(2 * c + 1) * HLEN] = v;
            svp[c8] = v; ssvp[c8] = v * v;
        }
#pragma unroll
        for (int off = 2; off < 64; off <<= 1) {
#pragma unroll
            for (int c8 = 0; c8 < 8; ++c8) {
                svp[c8]  += __shfl_xor(svp[c8], off);
                ssvp[c8] += __shfl_xor(ssvp[c8], off);
            }
        }
        if ((t & 62) == 0) {
#pragma unroll
            for (int c8 = 0; c8 < 8; ++c8) {
                int c = cbase + c8;
                atomicAdd(&accL[2 * c + 1][0], svp[c8]);
                atomicAdd(&accL[2 * c + 1][1], ssvp[c8]);
            }
        }
    }

    __syncthreads();

    // ---- sv via MFMA (f16) + fused stats ----
    {
        int w = t >> 6, l = t & 63;
        int lr = l & 15, lh = l >> 4;
        float s0 = 0.f, ss0 = 0.f;
#pragma unroll
        for (int it = 0; it < 2; ++it) {
            int itile = w * 2 + it;
            float4v acc = {0.f, 0.f, 0.f, 0.f};
#pragma unroll
            for (int ks = 0; ks < 4; ++ks) {
                half8v af = *(const half8v*)&Pl[itile * 16 + lr][ks * 32 + lh * 8];
                half8v bf = *(const half8v*)&vB[lr][ks * 32 + lh * 8];
                acc = __builtin_amdgcn_mfma_f32_16x16x32_f16(af, bf, acc, 0, 0, 0);
            }
            int oc = g * 32 + 2 * lr;
            float* sop = so + ((size_t)b * CQKV + oc) * HLEN + itile * 16 + lh * 4;
            float4 outv;
            outv.x = acc[0] * F_SV; outv.y = acc[1] * F_SV;
            outv.z = acc[2] * F_SV; outv.w = acc[3] * F_SV;
            *(float4*)sop = outv;
            s0  += outv.x + outv.y + outv.z + outv.w;
            ss0 += outv.x * outv.x + outv.y * outv.y + outv.z * outv.z + outv.w * outv.w;
        }
        s0  += __shfl_xor(s0, 16);  s0  += __shfl_xor(s0, 32);
        ss0 += __shfl_xor(ss0, 16); ss0 += __shfl_xor(ss0, 32);
        if (lh == 0) {
            atomicAdd(&accL[2 * lr][0], s0);
            atomicAdd(&accL[2 * lr][1], ss0);
        }
    }
    __syncthreads();
    if (t < 32) {
        int o = g * 32 + t;
        atomicAdd(&accF[(size_t)o * 2 + 0], (double)accL[t][0]);
        atomicAdd(&accF[(size_t)o * 2 + 1], (double)accL[t][1]);
    }
}

// ---------------------------------------------------------------------------
// Final affine + pair-sum + transpose (float4)
// ---------------------------------------------------------------------------
__global__ __launch_bounds__(256) void k_out(const float* __restrict__ so,
                                             const float* __restrict__ scale,
                                             const float* __restrict__ shift,
                                             float* __restrict__ out) {
    int b = blockIdx.x, n = b >> 6, wi = b & 63;
    int t = threadIdx.x;
    int h4  = (t & 31) << 2;
    int oc0 = (t >> 5) << 4;
    for (int k = 0; k < 16; ++k) {
        int oc = oc0 + k;
        float4 v0 = *(const float4*)(so + ((size_t)b * CQKV + 2 * oc) * HLEN + h4);
        float4 v1 = *(const float4*)(so + ((size_t)b * CQKV + 2 * oc + 1) * HLEN + h4);
        float s0 = scale[2 * oc], f0 = shift[2 * oc];
        float s1 = scale[2 * oc + 1], f1 = shift[2 * oc + 1];
        float4 o4;
        o4.x = fmaf(v0.x, s0, f0) + fmaf(v1.x, s1, f1);
        o4.y = fmaf(v0.y, s0, f0) + fmaf(v1.y, s1, f1);
        o4.z = fmaf(v0.z, s0, f0) + fmaf(v1.z, s1, f1);
        o4.w = fmaf(v0.w, s0, f0) + fmaf(v1.w, s1, f1);
        *(float4*)(out + (((size_t)n * 128 + oc) * 64 + wi) * HLEN + h4) = o4;
    }
}

extern "C" void kernel_launch(void* const* d_in, const int* in_sizes, int n_in,
                              void* d_out, int out_size, void* d_ws, size_t ws_size,
                              hipStream_t stream) {
    const float* x   = (const float*)d_in[0];
    const float* w   = (const float*)d_in[1];
    const float* g1  = (const float*)d_in[2];
    const float* b1  = (const float*)d_in[3];
    const float* g2  = (const float*)d_in[4];
    const float* b2  = (const float*)d_in[5];
    const float* gs  = (const float*)d_in[6];
    const float* bs  = (const float*)d_in[7];
    const float* go  = (const float*)d_in[8];
    const float* bo  = (const float*)d_in[9];
    const float* rel = (const float*)d_in[10];
    float* out = (float*)d_out;

    float*  qkv    = (float*)d_ws;                      // 16,777,216 f
    float*  so     = qkv + (size_t)16777216;            // 16,777,216 f
    double* accA   = (double*)(so + (size_t)16777216);  // 512 d
    double* accS   = accA + 512;                        // 48 d
    double* accF   = accS + 48;                         // 512 d
    float*  scaleA = (float*)(accF + 512);
    float*  shiftA = scaleA + 256;
    float*  scaleS = shiftA + 256;                      // 24
    float*  shiftS = scaleS + 24;
    float*  scaleF = shiftS + 24;                       // 256
    float*  shiftF = scaleF + 256;
    float*  Rq     = shiftF + 256;                      // 1024
    float*  Rk     = Rq + 1024;                         // 1024
    float*  TqT    = Rk + 1024;                         // 8192
    float*  TkT    = TqT + 8192;                        // 8192

    hipMemsetAsync(accA, 0, (512 + 48 + 512) * sizeof(double), stream);

    k_qkv<<<1024, 256, 0, stream>>>(x, w, qkv, accA);
    k_tables<<<128, 128, 0, stream>>>(rel, Rq, Rk, TqT, TkT);
    k_finA<<<1, 256, 0, stream>>>(accA, g1, g2, b2, scaleA, shiftA);
    k_gram<<<4096, 256, 0, stream>>>(qkv, scaleA, shiftA, Rq, Rk, TqT, TkT, accS);
    k_sfin<<<1, 32, 0, stream>>>(accS, gs, bs, scaleS, shiftS);
    k_attn<<<4096, 256, 0, stream>>>(qkv, scaleA, shiftA, rel, scaleS, shiftS, so, accF);
    k_finF<<<1, 256, 0, stream>>>(accF, go, bo, scaleF, shiftF);
    k_out<<<512, 256, 0, stream>>>(so, scaleF, shiftF, out);
}

// Round 12
// 313.404 us; speedup vs baseline: 1.9466x; 1.1006x over previous
//
#include <hip/hip_runtime.h>
#include <hip/hip_fp16.h>
#include <math.h>

#define B_TOT 512
#define CQKV  256
#define CIN   128
#define HLEN  128

static constexpr float F_QR = 0.3f, F_KR = 0.3f, F_SV = 0.5f, F_SVE = 0.3f;
static constexpr float EPS = 1e-5f;

typedef __attribute__((ext_vector_type(8))) short short8v;
typedef __attribute__((ext_vector_type(8))) _Float16 half8v;
typedef __attribute__((ext_vector_type(2))) _Float16 half2v;
typedef __attribute__((ext_vector_type(4))) float float4v;

#if __has_builtin(__builtin_amdgcn_fdot2)
#define HAVE_FDOT2 1
#endif

__device__ __forceinline__ unsigned short f2bf(float f) {
    unsigned u = __float_as_uint(f);
    unsigned r = u + 0x7fffu + ((u >> 16) & 1u);
    return (unsigned short)(r >> 16);
}
__device__ __forceinline__ unsigned short f2h(float f) {
    return __half_as_ushort(__float2half(f));
}

// ---------------------------------------------------------------------------
// Kernel 1 (MFMA): qkv GEMM + fused per-channel raw stats (round-11).
// ---------------------------------------------------------------------------
__global__ __launch_bounds__(256, 3) void k_qkv(const float* __restrict__ x,
                                                const float* __restrict__ w,
                                                float* __restrict__ qkv,
                                                double* __restrict__ accA) {
    __shared__ unsigned short As[64][136];
    __shared__ unsigned short Xs[256][64];
    __shared__ float wsum[64][2];
    int bid = blockIdx.x;
    int n   = bid >> 7;
    int sub = bid & 127;
    int mt  = sub >> 2;
    int ot  = sub & 3;
    int m0  = mt << 8;
    int o0  = ot << 6;
    int t   = threadIdx.x;

    if (t < 64) { wsum[t][0] = 0.f; wsum[t][1] = 0.f; }

#pragma unroll
    for (int it = 0; it < 8; ++it) {
        int idx = it * 256 + t;
        int o = idx >> 5, c4 = (idx & 31) << 2;
        float4 wv = *(const float4*)(w + (size_t)(o0 + o) * CIN + c4);
        As[o][c4 + 0] = f2bf(wv.x);
        As[o][c4 + 1] = f2bf(wv.y);
        As[o][c4 + 2] = f2bf(wv.z);
        As[o][c4 + 3] = f2bf(wv.w);
    }

    const float* xn = x + (size_t)n * CIN * 8192 + m0;

    int wv_ = t >> 6, l = t & 63;
    int lr = l & 15, lh = l >> 4;
    int mw = wv_ << 6;

    float4v acc[4][4];
#pragma unroll
    for (int a = 0; a < 4; ++a)
#pragma unroll
        for (int b2 = 0; b2 < 4; ++b2) acc[a][b2] = (float4v){0.f, 0.f, 0.f, 0.f};

    for (int s = 0; s < 2; ++s) {
        int c0 = s << 6;
        __syncthreads();
#pragma unroll
        for (int it = 0; it < 16; ++it) {
            int c  = (it << 2) + (t >> 6);
            int m4 = (t & 63) << 2;
            float4 xv = *(const float4*)(xn + (size_t)(c0 + c) * 8192 + m4);
            float vals[4] = {xv.x, xv.y, xv.z, xv.w};
#pragma unroll
            for (int j = 0; j < 4; ++j) {
                int m = m4 + j;
                int cs = (((c >> 3) ^ ((m >> 2) & 7)) << 3) | (c & 7);
                Xs[m][cs] = f2bf(vals[j]);
            }
        }
        __syncthreads();
#pragma unroll
        for (int ks = 0; ks < 2; ++ks) {
            short8v af[4], bf[4];
#pragma unroll
            for (int a = 0; a < 4; ++a)
                af[a] = *(const short8v*)&As[a * 16 + lr][c0 + ks * 32 + lh * 8];
#pragma unroll
            for (int b2 = 0; b2 < 4; ++b2) {
                int m  = mw + b2 * 16 + lr;
                int cb = (ks * 4 + lh) ^ ((m >> 2) & 7);
                bf[b2] = *(const short8v*)&Xs[m][cb << 3];
            }
#pragma unroll
            for (int a = 0; a < 4; ++a)
#pragma unroll
                for (int b2 = 0; b2 < 4; ++b2)
                    acc[a][b2] = __builtin_amdgcn_mfma_f32_16x16x32_bf16(
                        af[a], bf[b2], acc[a][b2], 0, 0, 0);
        }
    }

#pragma unroll
    for (int a = 0; a < 4; ++a) {
#pragma unroll
        for (int b2 = 0; b2 < 4; ++b2) {
            int m  = m0 + mw + b2 * 16 + lr;
            int bb = n * 64 + (m >> 7);
            int h  = m & 127;
#pragma unroll
            for (int r = 0; r < 4; ++r) {
                int o = o0 + a * 16 + lh * 4 + r;
                qkv[((size_t)bb * CQKV + o) * HLEN + h] = acc[a][b2][r];
            }
        }
    }

#pragma unroll
    for (int a = 0; a < 4; ++a) {
#pragma unroll
        for (int r = 0; r < 4; ++r) {
            float s = 0.f, ss = 0.f;
#pragma unroll
            for (int b2 = 0; b2 < 4; ++b2) {
                float v = acc[a][b2][r];
                s += v; ss += v * v;
            }
#pragma unroll
            for (int off = 1; off < 16; off <<= 1) {
                s  += __shfl_xor(s, off);
                ss += __shfl_xor(ss, off);
            }
            if (lr == 0) {
                int ol = a * 16 + lh * 4 + r;
                atomicAdd(&wsum[ol][0], s);
                atomicAdd(&wsum[ol][1], ss);
            }
        }
    }
    __syncthreads();
    if (t < 64) {
        atomicAdd(&accA[(size_t)(o0 + t) * 2 + 0], (double)wsum[t][0]);
        atomicAdd(&accA[(size_t)(o0 + t) * 2 + 1], (double)wsum[t][1]);
    }
}

__global__ void k_finA(const double* __restrict__ accA,
                       const float* __restrict__ g1, const float* __restrict__ g2,
                       const float* __restrict__ b2,
                       float* __restrict__ scaleA, float* __restrict__ shiftA) {
    int o = threadIdx.x;
    double cnt  = 65536.0;
    double mean = accA[o * 2] / cnt;
    double var  = accA[o * 2 + 1] / cnt - mean * mean;
    float r1 = rsqrtf((float)var + EPS);
    float v2 = g1[o] * g1[o] * (float)var * r1 * r1;
    float sc = g1[o] * g2[o] * r1 * rsqrtf(v2 + EPS);
    scaleA[o] = sc;
    shiftA[o] = b2[o] - (float)mean * sc;
}

__global__ void k_finF(const double* __restrict__ accF,
                       const float* __restrict__ go, const float* __restrict__ bo,
                       float* __restrict__ scaleF, float* __restrict__ shiftF) {
    int o = threadIdx.x;
    double cnt  = 65536.0;
    double mean = accF[o * 2] / cnt;
    double var  = accF[o * 2 + 1] / cnt - mean * mean;
    float sc = go[o] * rsqrtf((float)var + EPS);
    scaleF[o] = sc;
    shiftF[o] = bo[o] - (float)mean * sc;
}

// ---------------------------------------------------------------------------
// Tables for analytic score stats (f32, for k_gram).
// ---------------------------------------------------------------------------
__global__ __launch_bounds__(128) void k_tables(const float* __restrict__ rel,
                                                float* __restrict__ Rq, float* __restrict__ Rk,
                                                float* __restrict__ TqT, float* __restrict__ TkT) {
    int bid = blockIdx.x;      // 0..127
    int i = threadIdx.x;       // 0..127
    int p = bid & 63;
    int c = p >> 3, c2 = p & 7;
    const float* ra = (bid < 64) ? (rel + c * 255)  : (rel + (8 + c) * 255);
    const float* rb = (bid < 64) ? (rel + c2 * 255) : (rel + (8 + c2) * 255);
    float tacc = 0.f;
    for (int kk = 0; kk < 128; ++kk) tacc = fmaf(ra[i + kk], rb[i + kk], tacc);
    if (bid < 64) TqT[i * 64 + p] = tacc; else TkT[i * 64 + p] = tacc;
    if (c2 == 0) {
        float racc = 0.f;
        for (int kk = 0; kk < 128; ++kk) racc += ra[i + kk];
        if (bid < 64) Rq[c * 128 + i] = racc; else Rk[c * 128 + i] = racc;
    }
}

// ---------------------------------------------------------------------------
// Analytic score stats per (b,g) — 256 threads (round-11).
// ---------------------------------------------------------------------------
__global__ __launch_bounds__(256) void k_gram(const float* __restrict__ qkv,
                                              const float* __restrict__ scaleA,
                                              const float* __restrict__ shiftA,
                                              const float* __restrict__ Rq,
                                              const float* __restrict__ Rk,
                                              const float* __restrict__ TqT,
                                              const float* __restrict__ TkT,
                                              double* __restrict__ accS) {
    __shared__ float qs[8][132], ks[8][132];
    __shared__ float redA[4][64][4];
    __shared__ float redB[2][18];
    __shared__ float redC[3];
    int blk = blockIdx.x, b = blk >> 3, g = blk & 7;
    int t = threadIdx.x;
    for (int idx = t; idx < 2048; idx += 256) {
        int cc = idx >> 7, h = idx & 127, o = g * 32 + cc;
        float v = qkv[((size_t)b * CQKV + o) * HLEN + h] * scaleA[o] + shiftA[o];
        if (cc < 8) qs[cc][h] = v; else ks[cc - 8][h] = v;
    }
    __syncthreads();
    int lane = t & 63, wv = t >> 6;
    int c = lane >> 3, c2 = lane & 7;
    float gq = 0, gk = 0, tq = 0, tk = 0;
#pragma unroll 4
    for (int ii = 0; ii < 32; ++ii) {
        int i = wv * 32 + ii;
        float a = qs[c][i] * qs[c2][i];
        float e = ks[c][i] * ks[c2][i];
        gq += a; gk += e;
        tq = fmaf(a, TqT[i * 64 + lane], tq);
        tk = fmaf(e, TkT[i * 64 + lane], tk);
    }
    redA[wv][lane][0] = gq; redA[wv][lane][1] = gk;
    redA[wv][lane][2] = tq; redA[wv][lane][3] = tk;

    if (t < 128) {
        int h = t;
        float sqr = 0, skr = 0;
        float sq8l[8], sk8l[8];
#pragma unroll
        for (int c3 = 0; c3 < 8; ++c3) {
            float q0 = qs[c3][h], k0 = ks[c3][h];
            sq8l[c3] = q0; sk8l[c3] = k0;
            sqr = fmaf(q0, Rq[c3 * 128 + h], sqr);
            skr = fmaf(k0, Rk[c3 * 128 + h], skr);
        }
#pragma unroll
        for (int off = 1; off < 64; off <<= 1) {
            sqr += __shfl_xor(sqr, off);
            skr += __shfl_xor(skr, off);
#pragma unroll
            for (int c3 = 0; c3 < 8; ++c3) {
                sq8l[c3] += __shfl_xor(sq8l[c3], off);
                sk8l[c3] += __shfl_xor(sk8l[c3], off);
            }
        }
        if (lane == 0) {
            redB[wv][0] = sqr; redB[wv][1] = skr;
#pragma unroll
            for (int c3 = 0; c3 < 8; ++c3) {
                redB[wv][2 + c3]  = sq8l[c3];
                redB[wv][10 + c3] = sk8l[c3];
            }
        }
    }
    __syncthreads();
    if (t < 64) {
        float Gq = redA[0][t][0] + redA[1][t][0] + redA[2][t][0] + redA[3][t][0];
        float Gk = redA[0][t][1] + redA[1][t][1] + redA[2][t][1] + redA[3][t][1];
        float Tq = redA[0][t][2] + redA[1][t][2] + redA[2][t][2] + redA[3][t][2];
        float Tk = redA[0][t][3] + redA[1][t][3] + redA[2][t][3] + redA[3][t][3];
        float ssqk = Gq * Gk;
#pragma unroll
        for (int off = 1; off < 64; off <<= 1) {
            ssqk += __shfl_xor(ssqk, off);
            Tq   += __shfl_xor(Tq, off);
            Tk   += __shfl_xor(Tk, off);
        }
        if (t == 0) { redC[0] = ssqk; redC[1] = Tq; redC[2] = Tk; }
    }
    __syncthreads();
    if (t == 0) {
        float sqr = redB[0][0] + redB[1][0];
        float skr = redB[0][1] + redB[1][1];
        float sqk = 0;
#pragma unroll
        for (int c3 = 0; c3 < 8; ++c3)
            sqk += (redB[0][2 + c3] + redB[1][2 + c3]) * (redB[0][10 + c3] + redB[1][10 + c3]);
        atomicAdd(&accS[g * 2 + 0], (double)sqk);
        atomicAdd(&accS[g * 2 + 1], (double)redC[0]);
        atomicAdd(&accS[(8 + g) * 2 + 0], (double)(F_QR * sqr));
        atomicAdd(&accS[(8 + g) * 2 + 1], (double)(F_QR * F_QR * redC[1]));
        atomicAdd(&accS[(16 + g) * 2 + 0], (double)(F_KR * skr));
        atomicAdd(&accS[(16 + g) * 2 + 1], (double)(F_KR * F_KR * redC[2]));
    }
}

__global__ void k_sfin(const double* __restrict__ accS,
                       const float* __restrict__ gs, const float* __restrict__ bs,
                       float* __restrict__ scaleS, float* __restrict__ shiftS) {
    int c = threadIdx.x;
    if (c < 24) {
        double cnt  = 512.0 * 128.0 * 128.0;
        double mean = accS[c * 2] / cnt;
        double var  = accS[c * 2 + 1] / cnt - mean * mean;
        float sc = gs[c] * rsqrtf((float)var + EPS);
        scaleS[c] = sc;
        shiftS[c] = bs[c] - (float)mean * sc;
    }
}

// ---------------------------------------------------------------------------
// Attention — fragment-native: lane l of wave w computes scores for
// rows i = w*32 + it*16 + (l&15) (it=0,1), cols j = ks*32 + (l>>4)*8 + e.
// P stays in registers end-to-end (packed ph[32] u32 -> MFMA A-frag direct).
// No Pl LDS (-34KB -> 25.9KB -> 4 blocks/CU), no mid-kernel barriers.
// Row reductions via shfl_xor(16/32) (4 lanes share a row).
// ---------------------------------------------------------------------------
__global__ __launch_bounds__(256, 4) void k_attn(const float* __restrict__ qkv,
                                                 const float* __restrict__ scaleA,
                                                 const float* __restrict__ shiftA,
                                                 const float* __restrict__ rel,
                                                 const float* __restrict__ scaleS,
                                                 const float* __restrict__ shiftS,
                                                 float* __restrict__ so,
                                                 double* __restrict__ accF) {
    __shared__ unsigned short qT[128][8];
    __shared__ unsigned short kF[128][8];
    __shared__ unsigned short vB[16][136];
    __shared__ unsigned short rqT[255][8];
    __shared__ unsigned short rkT[255][8];
    __shared__ unsigned short rvA[255][8];
    __shared__ unsigned short rvB[255][8];
    __shared__ float accL[32][2];
    int blk = blockIdx.x, b = blk >> 3, g = blk & 7;
    int t = threadIdx.x;
    if (t < 32) { accL[t][0] = 0.f; accL[t][1] = 0.f; }

    // ---- staging: qkv via float4 ----
#pragma unroll
    for (int it = 0; it < 4; ++it) {
        int idx = it * 256 + t;
        int cc = idx >> 5;
        int h4 = (idx & 31) << 2;
        int o = g * 32 + cc;
        float4 v4 = *(const float4*)(qkv + ((size_t)b * CQKV + o) * HLEN + h4);
        float sc = scaleA[o], sh = shiftA[o];
        float f0 = fmaf(v4.x, sc, sh), f1 = fmaf(v4.y, sc, sh);
        float f2 = fmaf(v4.z, sc, sh), f3 = fmaf(v4.w, sc, sh);
        if (cc < 8) {
            qT[h4][cc] = f2h(f0); qT[h4 + 1][cc] = f2h(f1);
            qT[h4 + 2][cc] = f2h(f2); qT[h4 + 3][cc] = f2h(f3);
        } else if (cc < 16) {
            kF[h4][cc - 8] = f2h(f0); kF[h4 + 1][cc - 8] = f2h(f1);
            kF[h4 + 2][cc - 8] = f2h(f2); kF[h4 + 3][cc - 8] = f2h(f3);
        } else {
            uint2 pk;
            pk.x = (unsigned)f2h(f0) | ((unsigned)f2h(f1) << 16);
            pk.y = (unsigned)f2h(f2) | ((unsigned)f2h(f3) << 16);
            *(uint2*)&vB[cc - 16][h4] = pk;
        }
    }
    // ---- staging: rel via float4 ----
#pragma unroll
    for (int it = 0; it < 8; ++it) {
        int idx = it * 256 + t;
        if (idx < 2040) {
            float4 v = *(const float4*)(rel + (size_t)idx * 4);
            float vv[4] = {v.x, v.y, v.z, v.w};
#pragma unroll
            for (int e = 0; e < 4; ++e) {
                int lin = idx * 4 + e;
                int r = lin / 255;
                int d = lin - r * 255;
                unsigned short us = f2h(vv[e]);
                if (r < 8)       rqT[d][r] = us;
                else if (r < 16) rkT[d][r - 8] = us;
                else if (r < 24) rvA[d][r - 16] = us;
                else             rvB[d][r - 24] = us;
            }
        }
    }
    __syncthreads();

    float cA = scaleS[g], cB = F_QR * scaleS[8 + g], cC = F_KR * scaleS[16 + g];
    float shsum = shiftS[g] + shiftS[8 + g] + shiftS[16 + g];

    int w = t >> 6, l = t & 63;
    int lr = l & 15, lh = l >> 4;
    int i0 = w * 32 + lr;                   // row for it=0; it=1 row = i0+16

    half2v q2[2][4];
    {
        uint4 qv0 = *(const uint4*)&qT[i0][0];
        uint4 qv1 = *(const uint4*)&qT[i0 + 16][0];
        q2[0][0] = *(half2v*)&qv0.x; q2[0][1] = *(half2v*)&qv0.y;
        q2[0][2] = *(half2v*)&qv0.z; q2[0][3] = *(half2v*)&qv0.w;
        q2[1][0] = *(half2v*)&qv1.x; q2[1][1] = *(half2v*)&qv1.y;
        q2[1][2] = *(half2v*)&qv1.z; q2[1][3] = *(half2v*)&qv1.w;
    }

    float p0[32], p1[32];
    float rm0 = -1e30f, rm1 = -1e30f;
#pragma unroll
    for (int ks = 0; ks < 4; ++ks) {
#pragma unroll
        for (int e = 0; e < 8; ++e) {
            int j = ks * 32 + lh * 8 + e;
            uint4 kv = *(const uint4*)&kF[j][0];
            half2v* k2p = (half2v*)&kv;
#pragma unroll
            for (int it2 = 0; it2 < 2; ++it2) {
                int i = i0 + it2 * 16;
                uint4 rq = *(const uint4*)&rqT[i - j + 127][0];
                uint4 rk = *(const uint4*)&rkT[j - i + 127][0];
                half2v* rq2p = (half2v*)&rq;
                half2v* rk2p = (half2v*)&rk;
#ifdef HAVE_FDOT2
                float qk = __builtin_amdgcn_fdot2(q2[it2][0], k2p[0],
                           __builtin_amdgcn_fdot2(q2[it2][1], k2p[1],
                           __builtin_amdgcn_fdot2(q2[it2][2], k2p[2],
                           __builtin_amdgcn_fdot2(q2[it2][3], k2p[3], 0.f, false), false), false), false);
                float qr = __builtin_amdgcn_fdot2(q2[it2][0], rq2p[0],
                           __builtin_amdgcn_fdot2(q2[it2][1], rq2p[1],
                           __builtin_amdgcn_fdot2(q2[it2][2], rq2p[2],
                           __builtin_amdgcn_fdot2(q2[it2][3], rq2p[3], 0.f, false), false), false), false);
                float kr = __builtin_amdgcn_fdot2(k2p[0], rk2p[0],
                           __builtin_amdgcn_fdot2(k2p[1], rk2p[1],
                           __builtin_amdgcn_fdot2(k2p[2], rk2p[2],
                           __builtin_amdgcn_fdot2(k2p[3], rk2p[3], 0.f, false), false), false), false);
#else
                __half2* qh = (__half2*)&q2[it2][0];
                __half2* kk2 = (__half2*)&kv;
                __half2* rq2 = (__half2*)&rq;
                __half2* rk2 = (__half2*)&rk;
                __half2 hqk = __hfma2(qh[0], kk2[0], __hfma2(qh[1], kk2[1],
                              __hfma2(qh[2], kk2[2], __hmul2(qh[3], kk2[3]))));
                __half2 hqr = __hfma2(qh[0], rq2[0], __hfma2(qh[1], rq2[1],
                              __hfma2(qh[2], rq2[2], __hmul2(qh[3], rq2[3]))));
                __half2 hkr = __hfma2(kk2[0], rk2[0], __hfma2(kk2[1], rk2[1],
                              __hfma2(kk2[2], rk2[2], __hmul2(kk2[3], rk2[3]))));
                float qk = __low2float(hqk) + __high2float(hqk);
                float qr = __low2float(hqr) + __high2float(hqr);
                float kr = __low2float(hkr) + __high2float(hkr);
#endif
                float s = fmaf(qk, cA, fmaf(qr, cB, fmaf(kr, cC, shsum)));
                if (it2 == 0) { p0[ks * 8 + e] = s; rm0 = fmaxf(rm0, s); }
                else          { p1[ks * 8 + e] = s; rm1 = fmaxf(rm1, s); }
            }
        }
    }
    rm0 = fmaxf(rm0, __shfl_xor(rm0, 16)); rm0 = fmaxf(rm0, __shfl_xor(rm0, 32));
    rm1 = fmaxf(rm1, __shfl_xor(rm1, 16)); rm1 = fmaxf(rm1, __shfl_xor(rm1, 32));
    float rs0 = 0.f, rs1 = 0.f;
#pragma unroll
    for (int kk = 0; kk < 32; ++kk) {
        p0[kk] = __expf(p0[kk] - rm0); rs0 += p0[kk];
        p1[kk] = __expf(p1[kk] - rm1); rs1 += p1[kk];
    }
    rs0 += __shfl_xor(rs0, 16); rs0 += __shfl_xor(rs0, 32);
    rs1 += __shfl_xor(rs1, 16); rs1 += __shfl_xor(rs1, 32);
    float rn0 = 1.f / rs0, rn1 = 1.f / rs1;

    // ---- sve: raw-exp f16 accumulation (scale by F_SVE*rn at store) ----
    __half2 accA2[8], accB2[8];
#pragma unroll
    for (int m = 0; m < 8; ++m) {
        accA2[m] = __floats2half2_rn(0.f, 0.f);
        accB2[m] = __floats2half2_rn(0.f, 0.f);
    }
#pragma unroll
    for (int ks = 0; ks < 4; ++ks) {
#pragma unroll
        for (int e = 0; e < 8; ++e) {
            int j = ks * 32 + lh * 8 + e;
            {
                int d = i0 - j + 127;
                __half2 p2 = __float2half2_rn(p0[ks * 8 + e]);
                uint4 ra = *(const uint4*)&rvA[d][0];
                uint4 rb = *(const uint4*)&rvB[d][0];
                __half2* ra2 = (__half2*)&ra;
                __half2* rb2 = (__half2*)&rb;
                accA2[0] = __hfma2(p2, ra2[0], accA2[0]);
                accA2[1] = __hfma2(p2, ra2[1], accA2[1]);
                accA2[2] = __hfma2(p2, ra2[2], accA2[2]);
                accA2[3] = __hfma2(p2, ra2[3], accA2[3]);
                accA2[4] = __hfma2(p2, rb2[0], accA2[4]);
                accA2[5] = __hfma2(p2, rb2[1], accA2[5]);
                accA2[6] = __hfma2(p2, rb2[2], accA2[6]);
                accA2[7] = __hfma2(p2, rb2[3], accA2[7]);
            }
            {
                int d = i0 + 16 - j + 127;
                __half2 p2 = __float2half2_rn(p1[ks * 8 + e]);
                uint4 ra = *(const uint4*)&rvA[d][0];
                uint4 rb = *(const uint4*)&rvB[d][0];
                __half2* ra2 = (__half2*)&ra;
                __half2* rb2 = (__half2*)&rb;
                accB2[0] = __hfma2(p2, ra2[0], accB2[0]);
                accB2[1] = __hfma2(p2, ra2[1], accB2[1]);
                accB2[2] = __hfma2(p2, ra2[2], accB2[2]);
                accB2[3] = __hfma2(p2, ra2[3], accB2[3]);
                accB2[4] = __hfma2(p2, rb2[0], accB2[4]);
                accB2[5] = __hfma2(p2, rb2[1], accB2[5]);
                accB2[6] = __hfma2(p2, rb2[2], accB2[6]);
                accB2[7] = __hfma2(p2, rb2[3], accB2[7]);
            }
        }
    }
    // reduce rows over the 4 lanes sharing (w, lr)
#pragma unroll
    for (int m = 0; m < 8; ++m) {
        unsigned ua = *(unsigned*)&accA2[m];
        unsigned t1 = __shfl_xor(ua, 16);
        accA2[m] = __hadd2(accA2[m], *(__half2*)&t1);
        ua = *(unsigned*)&accA2[m];
        t1 = __shfl_xor(ua, 32);
        accA2[m] = __hadd2(accA2[m], *(__half2*)&t1);
        unsigned ub = *(unsigned*)&accB2[m];
        unsigned t2 = __shfl_xor(ub, 16);
        accB2[m] = __hadd2(accB2[m], *(__half2*)&t2);
        ub = *(unsigned*)&accB2[m];
        t2 = __shfl_xor(ub, 32);
        accB2[m] = __hadd2(accB2[m], *(__half2*)&t2);
    }
    // lane (lh) owns channels lh*4..lh*4+3; store + stats
    {
        float sce0 = F_SVE * rn0, sce1 = F_SVE * rn1;
        float s_c[4], ss_c[4];
#pragma unroll
        for (int cc = 0; cc < 4; ++cc) {
            int c = lh * 4 + cc;
            __half2 ha = accA2[c >> 1];
            __half2 hb = accB2[c >> 1];
            float v0 = ((c & 1) ? __high2float(ha) : __low2float(ha)) * sce0;
            float v1 = ((c & 1) ? __high2float(hb) : __low2float(hb)) * sce1;
            size_t base = ((size_t)b * CQKV + g * 32 + 2 * c + 1) * HLEN;
            so[base + i0]      = v0;
            so[base + i0 + 16] = v1;
            s_c[cc]  = v0 + v1;
            ss_c[cc] = v0 * v0 + v1 * v1;
        }
#pragma unroll
        for (int off = 1; off < 16; off <<= 1) {
#pragma unroll
            for (int cc = 0; cc < 4; ++cc) {
                s_c[cc]  += __shfl_xor(s_c[cc], off);
                ss_c[cc] += __shfl_xor(ss_c[cc], off);
            }
        }
        if (lr == 0) {
#pragma unroll
            for (int cc = 0; cc < 4; ++cc) {
                int c = lh * 4 + cc;
                atomicAdd(&accL[2 * c + 1][0], s_c[cc]);
                atomicAdd(&accL[2 * c + 1][1], ss_c[cc]);
            }
        }
    }

    // ---- pack P*rn into A-fragment registers ----
    unsigned ph[32];
#pragma unroll
    for (int ks = 0; ks < 4; ++ks) {
#pragma unroll
        for (int e2 = 0; e2 < 4; ++e2) {
            __half2 h0 = __floats2half2_rn(p0[ks * 8 + 2 * e2] * rn0,
                                           p0[ks * 8 + 2 * e2 + 1] * rn0);
            __half2 h1 = __floats2half2_rn(p1[ks * 8 + 2 * e2] * rn1,
                                           p1[ks * 8 + 2 * e2 + 1] * rn1);
            ph[ks * 4 + e2]      = *(unsigned*)&h0;
            ph[16 + ks * 4 + e2] = *(unsigned*)&h1;
        }
    }

    // ---- sv via MFMA (A direct from registers) + fused stats ----
    {
        float s0 = 0.f, ss0 = 0.f;
#pragma unroll
        for (int it2 = 0; it2 < 2; ++it2) {
            int itile = w * 2 + it2;
            float4v acc = {0.f, 0.f, 0.f, 0.f};
#pragma unroll
            for (int ks = 0; ks < 4; ++ks) {
                half8v af = *(half8v*)&ph[it2 * 16 + ks * 4];
                half8v bf = *(const half8v*)&vB[lr][ks * 32 + lh * 8];
                acc = __builtin_amdgcn_mfma_f32_16x16x32_f16(af, bf, acc, 0, 0, 0);
            }
            int oc = g * 32 + 2 * lr;
            float* sop = so + ((size_t)b * CQKV + oc) * HLEN + itile * 16 + lh * 4;
            float4 outv;
            outv.x = acc[0] * F_SV; outv.y = acc[1] * F_SV;
            outv.z = acc[2] * F_SV; outv.w = acc[3] * F_SV;
            *(float4*)sop = outv;
            s0  += outv.x + outv.y + outv.z + outv.w;
            ss0 += outv.x * outv.x + outv.y * outv.y + outv.z * outv.z + outv.w * outv.w;
        }
        s0  += __shfl_xor(s0, 16);  s0  += __shfl_xor(s0, 32);
        ss0 += __shfl_xor(ss0, 16); ss0 += __shfl_xor(ss0, 32);
        if (lh == 0) {
            atomicAdd(&accL[2 * lr][0], s0);
            atomicAdd(&accL[2 * lr][1], ss0);
        }
    }
    __syncthreads();
    if (t < 32) {
        int o = g * 32 + t;
        atomicAdd(&accF[(size_t)o * 2 + 0], (double)accL[t][0]);
        atomicAdd(&accF[(size_t)o * 2 + 1], (double)accL[t][1]);
    }
}

// ---------------------------------------------------------------------------
// Final affine + pair-sum + transpose (float4)
// ---------------------------------------------------------------------------
__global__ __launch_bounds__(256) void k_out(const float* __restrict__ so,
                                             const float* __restrict__ scale,
                                             const float* __restrict__ shift,
                                             float* __restrict__ out) {
    int b = blockIdx.x, n = b >> 6, wi = b & 63;
    int t = threadIdx.x;
    int h4  = (t & 31) << 2;
    int oc0 = (t >> 5) << 4;
    for (int k = 0; k < 16; ++k) {
        int oc = oc0 + k;
        float4 v0 = *(const float4*)(so + ((size_t)b * CQKV + 2 * oc) * HLEN + h4);
        float4 v1 = *(const float4*)(so + ((size_t)b * CQKV + 2 * oc + 1) * HLEN + h4);
        float s0 = scale[2 * oc], f0 = shift[2 * oc];
        float s1 = scale[2 * oc + 1], f1 = shift[2 * oc + 1];
        float4 o4;
        o4.x = fmaf(v0.x, s0, f0) + fmaf(v1.x, s1, f1);
        o4.y = fmaf(v0.y, s0, f0) + fmaf(v1.y, s1, f1);
        o4.z = fmaf(v0.z, s0, f0) + fmaf(v1.z, s1, f1);
        o4.w = fmaf(v0.w, s0, f0) + fmaf(v1.w, s1, f1);
        *(float4*)(out + (((size_t)n * 128 + oc) * 64 + wi) * HLEN + h4) = o4;
    }
}

extern "C" void kernel_launch(void* const* d_in, const int* in_sizes, int n_in,
                              void* d_out, int out_size, void* d_ws, size_t ws_size,
                              hipStream_t stream) {
    const float* x   = (const float*)d_in[0];
    const float* w   = (const float*)d_in[1];
    const float* g1  = (const float*)d_in[2];
    const float* b1  = (const float*)d_in[3];
    const float* g2  = (const float*)d_in[4];
    const float* b2  = (const float*)d_in[5];
    const float* gs  = (const float*)d_in[6];
    const float* bs  = (const float*)d_in[7];
    const float* go  = (const float*)d_in[8];
    const float* bo  = (const float*)d_in[9];
    const float* rel = (const float*)d_in[10];
    float* out = (float*)d_out;

    float*  qkv    = (float*)d_ws;                      // 16,777,216 f
    float*  so     = qkv + (size_t)16777216;            // 16,777,216 f
    double* accA   = (double*)(so + (size_t)16777216);  // 512 d
    double* accS   = accA + 512;                        // 48 d
    double* accF   = accS + 48;                         // 512 d
    float*  scaleA = (float*)(accF + 512);
    float*  shiftA = scaleA + 256;
    float*  scaleS = shiftA + 256;                      // 24
    float*  shiftS = scaleS + 24;
    float*  scaleF = shiftS + 24;                       // 256
    float*  shiftF = scaleF + 256;
    float*  Rq     = shiftF + 256;                      // 1024
    float*  Rk     = Rq + 1024;                         // 1024
    float*  TqT    = Rk + 1024;                         // 8192
    float*  TkT    = TqT + 8192;                        // 8192

    hipMemsetAsync(accA, 0, (512 + 48 + 512) * sizeof(double), stream);

    k_qkv<<<1024, 256, 0, stream>>>(x, w, qkv, accA);
    k_tables<<<128, 128, 0, stream>>>(rel, Rq, Rk, TqT, TkT);
    k_finA<<<1, 256, 0, stream>>>(accA, g1, g2, b2, scaleA, shiftA);
    k_gram<<<4096, 256, 0, stream>>>(qkv, scaleA, shiftA, Rq, Rk, TqT, TkT, accS);
    k_sfin<<<1, 32, 0, stream>>>(accS, gs, bs, scaleS, shiftS);
    k_attn<<<4096, 256, 0, stream>>>(qkv, scaleA, shiftA, rel, scaleS, shiftS, so, accF);
    k_finF<<<1, 256, 0, stream>>>(accF, go, bo, scaleF, shiftF);
    k_out<<<512, 256, 0, stream>>>(so, scaleF, shiftF, out);
}